// Round 11
// baseline (218.489 us; speedup 1.0000x reference)
//
#include <hip/hip_runtime.h>
#include <hip/hip_fp16.h>

#define N_NODES 100000
#define N_EDGES 3200000
#define DIM 128
#define NB 1000        // dst buckets
#define NPB 100        // nodes per bucket (NB*NPB == N_NODES exactly)
#define CAP 3840       // fixed slots per bucket: mean 3200, sigma ~57 -> +11.3 sigma
#define SBIN 32        // coarse src bins per node (src>>12 -> 0..24); 1 MB window

typedef _Float16 f16;
typedef f16 f16x8 __attribute__((ext_vector_type(8)));
typedef float f32x4 __attribute__((ext_vector_type(4)));

// dst/100 via magic multiply (exact for dst < 2^30)
__device__ __forceinline__ int bucket_of(int dst) {
    return (int)(((unsigned long long)(unsigned)dst * 42949673ull) >> 32);
}

// ---- A0 (middle path only): global per-bucket edge counts ----
__global__ void __launch_bounds__(256) a0_hist(const int* __restrict__ dst,
                                               int* __restrict__ ghist) {
    __shared__ int h[NB];
    for (int i = threadIdx.x; i < NB; i += 256) h[i] = 0;
    __syncthreads();
    const int base = blockIdx.x * 4096 + threadIdx.x;
    #pragma unroll
    for (int i = 0; i < 16; ++i) {
        int e = base + i * 256;
        if (e < N_EDGES) atomicAdd(&h[bucket_of(dst[e])], 1);
    }
    __syncthreads();
    for (int i = threadIdx.x; i < NB; i += 256)
        if (h[i]) atomicAdd(&ghist[i], h[i]);
}

// ---- scan of 1000 bucket counts -> base[], cursor[] (middle path only) ----
__global__ void __launch_bounds__(1024) bscan_kernel(const int* __restrict__ ghist,
                                                     int* __restrict__ base,
                                                     int* __restrict__ cursor) {
    __shared__ int buf[1024];
    const int v = (threadIdx.x < NB) ? ghist[threadIdx.x] : 0;
    buf[threadIdx.x] = v;
    __syncthreads();
    for (int off = 1; off < 1024; off <<= 1) {
        int t = (threadIdx.x >= off) ? buf[threadIdx.x - off] : 0;
        __syncthreads();
        buf[threadIdx.x] += t;
        __syncthreads();
    }
    if (threadIdx.x < NB) {
        int excl = buf[threadIdx.x] - v;
        base[threadIdx.x] = excl;
        cursor[threadIdx.x] = excl;
    }
    if (threadIdx.x == NB - 1) base[NB] = buf[threadIdx.x];
}

// ---- A1: place edges grouped by bucket; word = (src<<7)|local_dst ----
// LDS-staged: scatter into eloc[] (LDS tolerates scatter), then per-wave
// coalesced copy-out of whole bucket runs -> ~4x fewer L2 write transactions.
#define A1_CHUNK 8192
#define A1_BLK 1024
#define A1_ITER (A1_CHUNK / A1_BLK)   // 8
__global__ void __launch_bounds__(A1_BLK) a1_fill(const int* __restrict__ src,
                                                  const int* __restrict__ dst,
                                                  int* __restrict__ cursor,
                                                  unsigned* __restrict__ ebuf,
                                                  const int fixed) {
    __shared__ unsigned eloc[A1_CHUNK];           // 32 KB staging
    __shared__ int hcnt[NB], lexcl[NB], off[NB], rk[NB];
    __shared__ int psum[A1_BLK];
    const int tid = threadIdx.x;
    for (int i = tid; i < NB; i += A1_BLK) { hcnt[i] = 0; rk[i] = 0; }
    __syncthreads();
    const int cbase = blockIdx.x * A1_CHUNK;
    int dc[A1_ITER];
    #pragma unroll
    for (int j = 0; j < A1_ITER; ++j) {
        int e = cbase + j * A1_BLK + tid;
        int d = (e < N_EDGES) ? dst[e] : -1;
        dc[j] = d;
        if (d >= 0) atomicAdd(&hcnt[bucket_of(d)], 1);
    }
    __syncthreads();
    // exclusive scan of hcnt -> lexcl (local positions inside eloc)
    {
        int v = (tid < NB) ? hcnt[tid] : 0;
        psum[tid] = v;
        __syncthreads();
        for (int o = 1; o < A1_BLK; o <<= 1) {
            int t = (tid >= o) ? psum[tid - o] : 0;
            __syncthreads();
            psum[tid] += t;
            __syncthreads();
        }
        if (tid < NB) lexcl[tid] = psum[tid] - v;
    }
    // grab global windows
    for (int i = tid; i < NB; i += A1_BLK) {
        int c = hcnt[i];
        int o = c ? atomicAdd(&cursor[i], c) : 0;
        off[i] = (fixed ? i * CAP : 0) + o;
    }
    __syncthreads();
    // scatter into LDS (banked, cheap)
    #pragma unroll
    for (int j = 0; j < A1_ITER; ++j) {
        int d = dc[j];
        if (d >= 0) {
            int e = cbase + j * A1_BLK + tid;
            int b = bucket_of(d);
            int r = atomicAdd(&rk[b], 1);
            eloc[lexcl[b] + r] = ((unsigned)src[e] << 7) | (unsigned)(d - b * NPB);
        }
    }
    __syncthreads();
    // coalesced copy-out: wave w handles buckets w, w+16, ...
    const int wid = tid >> 6, lane = tid & 63;
    for (int b = wid; b < NB; b += A1_BLK / 64) {
        int cnt = hcnt[b];
        int lb = lexcl[b];
        int gb = off[b];
        bool guard = !fixed || (gb + cnt <= (b + 1) * CAP);  // never taken in practice
        if (guard)
            for (int k = lane; k < cnt; k += 64) ebuf[gb + k] = eloc[lb + k];
        else
            for (int k = lane; gb + k < (b + 1) * CAP && k < cnt; k += 64)
                ebuf[gb + k] = eloc[lb + k];
    }
}

// ---- B1: per-bucket counting sort by (local_dst, src>>12) ------------------
// Place pass scatters into LDS sorted[]; copy-out to csr is fully coalesced.
#define B1_BLK 512
__global__ void __launch_bounds__(B1_BLK) b1_sort(const unsigned* __restrict__ ebuf,
                                                  const int* __restrict__ base,   // exact path
                                                  const int* __restrict__ cnts,   // fixed path
                                                  const int fixed,
                                                  int* __restrict__ csr,
                                                  int* __restrict__ row_beg,
                                                  int* __restrict__ row_end,
                                                  float* __restrict__ norm) {
    __shared__ int hist[NPB * SBIN], cur[NPB * SBIN], psum[B1_BLK];
    __shared__ int sorted[CAP];                    // 15.4 KB staging
    const int b = blockIdx.x, tid = threadIdx.x;
    int beg, cnt;
    if (fixed) { beg = b * CAP; cnt = min(cnts[b], CAP); }
    else       { beg = base[b]; cnt = base[b + 1] - beg; }
    const int end = beg + cnt;
    for (int i = tid; i < NPB * SBIN; i += B1_BLK) { hist[i] = 0; cur[i] = 0; }
    __syncthreads();
    for (int i = beg + tid; i < end; i += B1_BLK) {
        unsigned w = ebuf[i];
        int key = (int)(w & 127u) * SBIN + (int)(w >> 19);   // src>>12
        atomicAdd(&hist[key], 1);
    }
    __syncthreads();
    // in-place exclusive scan of 3200 counters: 7-elem chunks + block scan
    {
        int s = 0;
        const int c0 = tid * 7;
        #pragma unroll
        for (int j = 0; j < 7; ++j) {
            int idx = c0 + j;
            if (idx < NPB * SBIN) { int hh = hist[idx]; hist[idx] = s; s += hh; }
        }
        psum[tid] = s;
    }
    __syncthreads();
    for (int off = 1; off < B1_BLK; off <<= 1) {
        int t = (tid >= off) ? psum[tid - off] : 0;
        __syncthreads();
        psum[tid] += t;
        __syncthreads();
    }
    {
        int add = (tid > 0) ? psum[tid - 1] : 0;
        const int c0 = tid * 7;
        #pragma unroll
        for (int j = 0; j < 7; ++j) {
            int idx = c0 + j;
            if (idx < NPB * SBIN) hist[idx] += add;
        }
    }
    __syncthreads();
    if (tid < NPB) {
        int st = hist[tid * SBIN];
        int nx = (tid == NPB - 1) ? cnt : hist[(tid + 1) * SBIN];
        row_beg[b * NPB + tid] = beg + st;
        row_end[b * NPB + tid] = beg + nx;
        norm[b * NPB + tid] = rsqrtf(fmaxf((float)(nx - st), 1.0f));
    }
    __syncthreads();
    // scatter into LDS sorted[] (cheap), not global
    for (int i = beg + tid; i < end; i += B1_BLK) {
        unsigned w = ebuf[i];
        int s = (int)(w >> 7);
        int key = (int)(w & 127u) * SBIN + (s >> 12);
        int r = atomicAdd(&cur[key], 1);
        sorted[hist[key] + r] = s;
    }
    __syncthreads();
    // coalesced copy-out
    for (int i = tid; i < cnt; i += B1_BLK) csr[beg + i] = sorted[i];
}

// ---- preGEMM via MFMA: g16[n] = fp16(norm[n] * (feat[n] @ W^T)) -------------
#define PG_NBLK 512
#define PG_NTILE ((N_NODES + 63) / 64)   // 1563, last tile partial
__global__ void __launch_bounds__(256, 2) pregemm_mfma(const float* __restrict__ feat,
                                                       const float* __restrict__ W,
                                                       const float* __restrict__ norm,
                                                       __half* __restrict__ g16) {
    const int wid = threadIdx.x >> 6;
    const int l   = threadIdx.x & 63;
    const int lr  = l & 15;             // A-row / B-col / C-col
    const int lk  = (l >> 4) * 8;       // k-offset base

    f16x8 bf[8][4];
    #pragma unroll
    for (int nt = 0; nt < 8; ++nt) {
        #pragma unroll
        for (int kb = 0; kb < 4; ++kb) {
            const float* wp = W + (size_t)(nt * 16 + lr) * DIM + kb * 32 + lk;
            float4 w0 = *reinterpret_cast<const float4*>(wp);
            float4 w1 = *reinterpret_cast<const float4*>(wp + 4);
            f16x8 t;
            t[0] = (f16)w0.x; t[1] = (f16)w0.y; t[2] = (f16)w0.z; t[3] = (f16)w0.w;
            t[4] = (f16)w1.x; t[5] = (f16)w1.y; t[6] = (f16)w1.z; t[7] = (f16)w1.w;
            bf[nt][kb] = t;
        }
    }

    for (int tile = blockIdx.x; tile < PG_NTILE; tile += PG_NBLK) {
        const int r0 = tile * 64 + wid * 16;
        if (r0 >= N_NODES) continue;
        f32x4 acc[8] = {};
        #pragma unroll
        for (int kb = 0; kb < 4; ++kb) {
            int ar = r0 + lr;
            if (ar >= N_NODES) ar = N_NODES - 1;
            const float* ap = feat + (size_t)ar * DIM + kb * 32 + lk;
            float4 a0 = *reinterpret_cast<const float4*>(ap);
            float4 a1 = *reinterpret_cast<const float4*>(ap + 4);
            f16x8 a;
            a[0] = (f16)a0.x; a[1] = (f16)a0.y; a[2] = (f16)a0.z; a[3] = (f16)a0.w;
            a[4] = (f16)a1.x; a[5] = (f16)a1.y; a[6] = (f16)a1.z; a[7] = (f16)a1.w;
            #pragma unroll
            for (int nt = 0; nt < 8; ++nt)
                acc[nt] = __builtin_amdgcn_mfma_f32_16x16x32_f16(a, bf[nt][kb], acc[nt], 0, 0, 0);
        }
        const int orow0 = r0 + (l >> 4) * 4;
        float nrm[4];
        #pragma unroll
        for (int j = 0; j < 4; ++j)
            nrm[j] = (orow0 + j < N_NODES) ? norm[orow0 + j] : 0.f;
        #pragma unroll
        for (int nt = 0; nt < 8; ++nt) {
            #pragma unroll
            for (int j = 0; j < 4; ++j) {
                int row = orow0 + j;
                if (row < N_NODES)
                    g16[(size_t)row * DIM + nt * 16 + lr] =
                        __float2half(acc[nt][j] * nrm[j]);
            }
        }
    }
}

// ---- gather2: one wave per node; two rows per load; 8 loads in flight -------
// XCD-chunked swizzle: XCD k owns contiguous node range.
#define G2_NBLK (N_NODES / 4)            // 25000, % 8 == 0 (bijective swizzle)
__global__ void __launch_bounds__(256) gather2(const __half* __restrict__ g16,
                                               const float* __restrict__ norm,
                                               const float* __restrict__ feat,
                                               const int* __restrict__ row_beg,
                                               const int* __restrict__ row_end,
                                               const int* __restrict__ csr,
                                               float* __restrict__ out) {
    const int bswz = (blockIdx.x & 7) * (G2_NBLK / 8) + (blockIdx.x >> 3);
    const int n = bswz * 4 + (threadIdx.x >> 6);
    const int l = threadIdx.x & 63;
    const int sub = l >> 5, li = l & 31;
    const int beg = row_beg[n];
    const int end = row_end[n];
    float a0 = 0.f, a1 = 0.f, a2 = 0.f, a3 = 0.f;
    int e = beg;
    for (; e + 15 < end; e += 16) {      // 8 independent in-flight loads
        int s[8];
        #pragma unroll
        for (int j = 0; j < 8; ++j) s[j] = csr[e + 2 * j + sub];
        uint2 u[8];
        #pragma unroll
        for (int j = 0; j < 8; ++j)
            u[j] = reinterpret_cast<const uint2*>(g16 + (size_t)s[j] * DIM)[li];
        #pragma unroll
        for (int j = 0; j < 8; ++j) {
            float2 p0 = __half22float2(*reinterpret_cast<__half2*>(&u[j].x));
            float2 p1 = __half22float2(*reinterpret_cast<__half2*>(&u[j].y));
            a0 += p0.x; a1 += p0.y; a2 += p1.x; a3 += p1.y;
        }
    }
    for (; e + 7 < end; e += 8) {
        int s[4];
        #pragma unroll
        for (int j = 0; j < 4; ++j) s[j] = csr[e + 2 * j + sub];
        uint2 u[4];
        #pragma unroll
        for (int j = 0; j < 4; ++j)
            u[j] = reinterpret_cast<const uint2*>(g16 + (size_t)s[j] * DIM)[li];
        #pragma unroll
        for (int j = 0; j < 4; ++j) {
            float2 p0 = __half22float2(*reinterpret_cast<__half2*>(&u[j].x));
            float2 p1 = __half22float2(*reinterpret_cast<__half2*>(&u[j].y));
            a0 += p0.x; a1 += p0.y; a2 += p1.x; a3 += p1.y;
        }
    }
    for (; e + 1 < end; e += 2) {
        const int s = csr[e + sub];
        uint2 u = reinterpret_cast<const uint2*>(g16 + (size_t)s * DIM)[li];
        float2 p0 = __half22float2(*reinterpret_cast<__half2*>(&u.x));
        float2 p1 = __half22float2(*reinterpret_cast<__half2*>(&u.y));
        a0 += p0.x; a1 += p0.y; a2 += p1.x; a3 += p1.y;
    }
    if (e < end) {                       // odd leftover: half 0 only
        const int s = csr[e];
        uint2 u = reinterpret_cast<const uint2*>(g16 + (size_t)s * DIM)[li];
        if (sub == 0) {
            float2 p0 = __half22float2(*reinterpret_cast<__half2*>(&u.x));
            float2 p1 = __half22float2(*reinterpret_cast<__half2*>(&u.y));
            a0 += p0.x; a1 += p0.y; a2 += p1.x; a3 += p1.y;
        }
    }
    // combine the two half-wave partials
    a0 += __shfl_xor(a0, 32);
    a1 += __shfl_xor(a1, 32);
    a2 += __shfl_xor(a2, 32);
    a3 += __shfl_xor(a3, 32);
    if (sub == 0) {
        const float nm = norm[n];
        const float4 f = reinterpret_cast<const float4*>(feat + (size_t)n * DIM)[li];
        float4 o;
        o.x = fmaxf(a0 * nm, 0.f) + f.x;
        o.y = fmaxf(a1 * nm, 0.f) + f.y;
        o.z = fmaxf(a2 * nm, 0.f) + f.z;
        o.w = fmaxf(a3 * nm, 0.f) + f.w;
        reinterpret_cast<float4*>(out + (size_t)n * DIM)[li] = o;
    }
}

// ============================ FALLBACK (round-2 path) =======================
#define SCAN_B 1024
#define N_SCANB ((N_NODES + SCAN_B - 1) / SCAN_B)

__global__ void __launch_bounds__(256) deg_kernel(const int* __restrict__ dst,
                                                  int* __restrict__ deg) {
    int i = blockIdx.x * 256 + threadIdx.x;
    if (i < N_EDGES) atomicAdd(&deg[dst[i]], 1);
}
__global__ void __launch_bounds__(SCAN_B) scan1_kernel(const int* __restrict__ deg,
                                                       int* __restrict__ excl,
                                                       int* __restrict__ partials) {
    __shared__ int buf[SCAN_B];
    const int gid = blockIdx.x * SCAN_B + threadIdx.x;
    const int v = (gid < N_NODES) ? deg[gid] : 0;
    buf[threadIdx.x] = v;
    __syncthreads();
    #pragma unroll
    for (int off = 1; off < SCAN_B; off <<= 1) {
        int t = (threadIdx.x >= off) ? buf[threadIdx.x - off] : 0;
        __syncthreads();
        buf[threadIdx.x] += t;
        __syncthreads();
    }
    if (gid < N_NODES) excl[gid] = buf[threadIdx.x] - v;
    if (threadIdx.x == SCAN_B - 1) partials[blockIdx.x] = buf[threadIdx.x];
}
__global__ void __launch_bounds__(128) scan2_kernel(int* __restrict__ partials) {
    __shared__ int buf[128];
    const int v = (threadIdx.x < N_SCANB) ? partials[threadIdx.x] : 0;
    buf[threadIdx.x] = v;
    __syncthreads();
    #pragma unroll
    for (int off = 1; off < 128; off <<= 1) {
        int t = (threadIdx.x >= off) ? buf[threadIdx.x - off] : 0;
        __syncthreads();
        buf[threadIdx.x] += t;
        __syncthreads();
    }
    if (threadIdx.x < N_SCANB) partials[threadIdx.x] = buf[threadIdx.x] - v;
}
__global__ void __launch_bounds__(SCAN_B) scan3_kernel(
        const int* __restrict__ excl, const int* __restrict__ partials,
        const int* __restrict__ deg,
        int* __restrict__ row_start, int* __restrict__ cursor,
        float* __restrict__ norm) {
    const int gid = blockIdx.x * SCAN_B + threadIdx.x;
    if (gid < N_NODES) {
        const int rs = excl[gid] + partials[blockIdx.x];
        row_start[gid] = rs;
        cursor[gid] = rs;
        norm[gid] = rsqrtf(fmaxf((float)deg[gid], 1.0f));
    }
    if (gid == 0) row_start[N_NODES] = N_EDGES;
}
__global__ void __launch_bounds__(256) fill_kernel(
        const int* __restrict__ src, const int* __restrict__ dst,
        int* __restrict__ cursor, int* __restrict__ csr) {
    int i = blockIdx.x * 256 + threadIdx.x;
    if (i < N_EDGES) {
        int pos = atomicAdd(&cursor[dst[i]], 1);
        csr[pos] = src[i];
    }
}
__global__ void __launch_bounds__(256) gather_kernel(
        const float* __restrict__ feat, const float* __restrict__ norm,
        const int* __restrict__ row_start, const int* __restrict__ csr,
        float* __restrict__ out) {
    const int n = blockIdx.x * 4 + (threadIdx.x >> 6);
    if (n >= N_NODES) return;
    const int lane = threadIdx.x & 63;
    const int beg = row_start[n];
    const int end = row_start[n + 1];
    float2 acc = make_float2(0.f, 0.f);
    int e = beg;
    for (; e + 1 < end; e += 2) {
        const int s0 = csr[e], s1 = csr[e + 1];
        const float w0 = norm[s0], w1 = norm[s1];
        const float2 v0 = reinterpret_cast<const float2*>(feat + (size_t)s0 * DIM)[lane];
        const float2 v1 = reinterpret_cast<const float2*>(feat + (size_t)s1 * DIM)[lane];
        acc.x = fmaf(v0.x, w0, acc.x); acc.y = fmaf(v0.y, w0, acc.y);
        acc.x = fmaf(v1.x, w1, acc.x); acc.y = fmaf(v1.y, w1, acc.y);
    }
    if (e < end) {
        const int s0 = csr[e];
        const float w0 = norm[s0];
        const float2 v0 = reinterpret_cast<const float2*>(feat + (size_t)s0 * DIM)[lane];
        acc.x = fmaf(v0.x, w0, acc.x); acc.y = fmaf(v0.y, w0, acc.y);
    }
    reinterpret_cast<float2*>(out + (size_t)n * DIM)[lane] = acc;
}
__global__ void __launch_bounds__(256) final_kernel(
        const float* __restrict__ feat, const float* __restrict__ W,
        const float* __restrict__ norm, float* __restrict__ out) {
    __shared__ float Wt[DIM * DIM];
    __shared__ float rowbuf[8][DIM];
    for (int idx = threadIdx.x; idx < DIM * DIM; idx += 256)
        Wt[idx] = W[(idx & 127) * DIM + (idx >> 7)];
    const int o  = threadIdx.x & 127;
    const int r0 = (threadIdx.x >> 7) * 4;
    for (int rb = blockIdx.x * 8; rb < N_NODES; rb += gridDim.x * 8) {
        __syncthreads();
        float4 v = reinterpret_cast<const float4*>(out + (size_t)rb * DIM)[threadIdx.x];
        reinterpret_cast<float4*>(&rowbuf[0][0])[threadIdx.x] = v;
        __syncthreads();
        float acc0 = 0.f, acc1 = 0.f, acc2 = 0.f, acc3 = 0.f;
        #pragma unroll 8
        for (int k = 0; k < DIM; ++k) {
            float w = Wt[k * DIM + o];
            acc0 = fmaf(rowbuf[r0 + 0][k], w, acc0);
            acc1 = fmaf(rowbuf[r0 + 1][k], w, acc1);
            acc2 = fmaf(rowbuf[r0 + 2][k], w, acc2);
            acc3 = fmaf(rowbuf[r0 + 3][k], w, acc3);
        }
        float accs[4] = {acc0, acc1, acc2, acc3};
        #pragma unroll
        for (int r = 0; r < 4; ++r) {
            int row = rb + r0 + r;
            float val = fmaxf(accs[r] * norm[row], 0.0f) + feat[(size_t)row * DIM + o];
            out[(size_t)row * DIM + o] = val;
        }
    }
}

// ============================ launch ========================================
extern "C" void kernel_launch(void* const* d_in, const int* in_sizes, int n_in,
                              void* d_out, int out_size, void* d_ws, size_t ws_size,
                              hipStream_t stream) {
    const float* feat = (const float*)d_in[0];
    const float* W    = (const float*)d_in[1];
    const int*   src  = (const int*)d_in[2];
    const int*   dst  = (const int*)d_in[3];
    float* out = (float*)d_out;

    const size_t G16_BYTES  = (size_t)N_NODES * DIM * 2;      // 25.6 MB
    const size_t EBUF_FIX   = (size_t)NB * CAP * 4;           // 15.36 MB
    const size_t EBUF_EXACT = (size_t)N_EDGES * 4;            // 12.8 MB
    const int    A1_GRID    = (N_EDGES + A1_CHUNK - 1) / A1_CHUNK;   // 391

    // ---- fast path (fixed-capacity buckets), ~42.2 MB ----
    {
        char* p = (char*)d_ws;
        __half*   g16   = (__half*)p;
        unsigned* ebuf  = (unsigned*)p; p += (G16_BYTES > EBUF_FIX ? G16_BYTES : EBUF_FIX);
        int*      csr   = (int*)p;      p += EBUF_FIX;
        float*    norm  = (float*)p;    p += (size_t)N_NODES * 4;
        int*   row_beg  = (int*)p;      p += (size_t)N_NODES * 4;
        int*   row_end  = (int*)p;      p += (size_t)N_NODES * 4;
        int*   cursor   = (int*)p;      p += NB * 4;
        if (ws_size >= (size_t)(p - (char*)d_ws)) {
            hipMemsetAsync(cursor, 0, NB * sizeof(int), stream);
            a1_fill     <<<A1_GRID, A1_BLK, 0, stream>>>(src, dst, cursor, ebuf, 1);
            b1_sort     <<<NB, B1_BLK, 0, stream>>>(ebuf, nullptr, cursor, 1, csr, row_beg, row_end, norm);
            pregemm_mfma<<<PG_NBLK, 256, 0, stream>>>(feat, W, norm, g16);   // overwrites ebuf
            gather2     <<<G2_NBLK, 256, 0, stream>>>(g16, norm, feat, row_beg, row_end, csr, out);
            return;
        }
    }

    // ---- middle path (exact bases via a0+bscan), ~39.6 MB ----
    {
        char* p = (char*)d_ws;
        __half*   g16   = (__half*)p;
        unsigned* ebuf  = (unsigned*)p; p += (G16_BYTES > EBUF_EXACT ? G16_BYTES : EBUF_EXACT);
        int*      csr   = (int*)p;      p += EBUF_EXACT;
        float*    norm  = (float*)p;    p += (size_t)N_NODES * 4;
        int*   row_beg  = (int*)p;      p += (size_t)N_NODES * 4;
        int*   row_end  = (int*)p;      p += (size_t)N_NODES * 4;
        int*      ghist = (int*)p;      p += NB * 4;
        int*      bbase = (int*)p;      p += (NB + 4) * 4;
        int*      bcur  = (int*)p;      p += NB * 4;
        if (ws_size >= (size_t)(p - (char*)d_ws)) {
            hipMemsetAsync(ghist, 0, NB * sizeof(int), stream);
            a0_hist     <<<(N_EDGES + 4095) / 4096, 256, 0, stream>>>(dst, ghist);
            bscan_kernel<<<1, 1024, 0, stream>>>(ghist, bbase, bcur);
            a1_fill     <<<A1_GRID, A1_BLK, 0, stream>>>(src, dst, bcur, ebuf, 0);
            b1_sort     <<<NB, B1_BLK, 0, stream>>>(ebuf, bbase, nullptr, 0, csr, row_beg, row_end, norm);
            pregemm_mfma<<<PG_NBLK, 256, 0, stream>>>(feat, W, norm, g16);
            gather2     <<<G2_NBLK, 256, 0, stream>>>(g16, norm, feat, row_beg, row_end, csr, out);
            return;
        }
    }

    // ---- last-resort fallback (round-2 path, ~14.8 MB) ----
    {
        char* q = (char*)d_ws;
        int*   deg       = (int*)q;   q += N_NODES * sizeof(int);
        int*   excl      = (int*)q;   q += N_NODES * sizeof(int);
        int*   cursor    = (int*)q;   q += N_NODES * sizeof(int);
        int*   row_start2= (int*)q;   q += (N_NODES + 1) * sizeof(int);
        float* nrm       = (float*)q; q += N_NODES * sizeof(float);
        int*   partials  = (int*)q;   q += 128 * sizeof(int);
        int*   csr2      = (int*)q;

        hipMemsetAsync(deg, 0, (size_t)N_NODES * sizeof(int), stream);
        deg_kernel  <<<N_EDGES / 256, 256, 0, stream>>>(dst, deg);
        scan1_kernel<<<N_SCANB, SCAN_B, 0, stream>>>(deg, excl, partials);
        scan2_kernel<<<1, 128, 0, stream>>>(partials);
        scan3_kernel<<<N_SCANB, SCAN_B, 0, stream>>>(excl, partials, deg,
                                                     row_start2, cursor, nrm);
        fill_kernel <<<N_EDGES / 256, 256, 0, stream>>>(src, dst, cursor, csr2);
        gather_kernel<<<(N_NODES + 3) / 4, 256, 0, stream>>>(feat, nrm, row_start2, csr2, out);
        final_kernel<<<512, 256, 0, stream>>>(feat, W, nrm, out);
    }
}

// Round 12
// 168.027 us; speedup vs baseline: 1.3003x; 1.3003x over previous
//
#include <hip/hip_runtime.h>
#include <hip/hip_fp16.h>
#include <hip/hip_fp8.h>

#define N_NODES 100000
#define N_EDGES 3200000
#define DIM 128
#define NB 1000        // dst buckets
#define NPB 100        // nodes per bucket (NB*NPB == N_NODES exactly)
#define CAP 3840       // fixed slots per bucket: mean 3200, sigma ~57 -> +11.3 sigma
#define SBIN 32        // coarse src bins per node (src>>12 -> 0..24); 1 MB window

typedef _Float16 f16;
typedef f16 f16x8 __attribute__((ext_vector_type(8)));
typedef float f32x4 __attribute__((ext_vector_type(4)));
typedef float f32x2 __attribute__((ext_vector_type(2)));

// dst/100 via magic multiply (exact for dst < 2^30)
__device__ __forceinline__ int bucket_of(int dst) {
    return (int)(((unsigned long long)(unsigned)dst * 42949673ull) >> 32);
}

// ---- fp8 e4m3 (OCP on gfx950) encode/decode, HW cvt with header fallback ----
__device__ __forceinline__ unsigned char f32_to_fp8(float x) {
#if __has_builtin(__builtin_amdgcn_cvt_pk_fp8_f32)
    int r = __builtin_amdgcn_cvt_pk_fp8_f32(x, x, 0, false);
    return (unsigned char)(r & 0xff);
#else
    __hip_fp8_e4m3 q(x);
    return (unsigned char)q.__x;
#endif
}
__device__ __forceinline__ void fp8x4_acc(unsigned u, float& a0, float& a1,
                                          float& a2, float& a3) {
#if __has_builtin(__builtin_amdgcn_cvt_pk_f32_fp8)
    f32x2 lo = __builtin_amdgcn_cvt_pk_f32_fp8((int)u, false);
    f32x2 hi = __builtin_amdgcn_cvt_pk_f32_fp8((int)u, true);
    a0 += lo[0]; a1 += lo[1]; a2 += hi[0]; a3 += hi[1];
#else
    __hip_fp8_e4m3 q0, q1, q2, q3;
    q0.__x = (unsigned char)(u & 0xffu);
    q1.__x = (unsigned char)((u >> 8) & 0xffu);
    q2.__x = (unsigned char)((u >> 16) & 0xffu);
    q3.__x = (unsigned char)((u >> 24) & 0xffu);
    a0 += (float)q0; a1 += (float)q1; a2 += (float)q2; a3 += (float)q3;
#endif
}

// ---- A0 (middle path only): global per-bucket edge counts ----
__global__ void __launch_bounds__(256) a0_hist(const int* __restrict__ dst,
                                               int* __restrict__ ghist) {
    __shared__ int h[NB];
    for (int i = threadIdx.x; i < NB; i += 256) h[i] = 0;
    __syncthreads();
    const int base = blockIdx.x * 4096 + threadIdx.x;
    #pragma unroll
    for (int i = 0; i < 16; ++i) {
        int e = base + i * 256;
        if (e < N_EDGES) atomicAdd(&h[bucket_of(dst[e])], 1);
    }
    __syncthreads();
    for (int i = threadIdx.x; i < NB; i += 256)
        if (h[i]) atomicAdd(&ghist[i], h[i]);
}

// ---- scan of 1000 bucket counts -> base[], cursor[] (middle path only) ----
__global__ void __launch_bounds__(1024) bscan_kernel(const int* __restrict__ ghist,
                                                     int* __restrict__ base,
                                                     int* __restrict__ cursor) {
    __shared__ int buf[1024];
    const int v = (threadIdx.x < NB) ? ghist[threadIdx.x] : 0;
    buf[threadIdx.x] = v;
    __syncthreads();
    for (int off = 1; off < 1024; off <<= 1) {
        int t = (threadIdx.x >= off) ? buf[threadIdx.x - off] : 0;
        __syncthreads();
        buf[threadIdx.x] += t;
        __syncthreads();
    }
    if (threadIdx.x < NB) {
        int excl = buf[threadIdx.x] - v;
        base[threadIdx.x] = excl;
        cursor[threadIdx.x] = excl;
    }
    if (threadIdx.x == NB - 1) base[NB] = buf[threadIdx.x];
}

// ---- A1 (R10 version): 16384-edge chunks, 1024-thread blocks ----
#define A1_CHUNK 16384
#define A1_BLK 1024
#define A1_ITER (A1_CHUNK / A1_BLK)   // 16
__global__ void __launch_bounds__(A1_BLK) a1_fill(const int* __restrict__ src,
                                                  const int* __restrict__ dst,
                                                  int* __restrict__ cursor,
                                                  unsigned* __restrict__ ebuf,
                                                  const int fixed) {
    __shared__ int h[NB], off[NB], rk[NB];
    const int tid = threadIdx.x;
    for (int i = tid; i < NB; i += A1_BLK) { h[i] = 0; rk[i] = 0; }
    __syncthreads();
    const int cbase = blockIdx.x * A1_CHUNK;
    int dc[A1_ITER];
    #pragma unroll
    for (int j = 0; j < A1_ITER; ++j) {
        int e = cbase + j * A1_BLK + tid;
        int d = (e < N_EDGES) ? dst[e] : -1;
        dc[j] = d;
        if (d >= 0) atomicAdd(&h[bucket_of(d)], 1);
    }
    __syncthreads();
    for (int i = tid; i < NB; i += A1_BLK) {
        int c = h[i];
        int o = c ? atomicAdd(&cursor[i], c) : 0;
        off[i] = (fixed ? i * CAP : 0) + o;
    }
    __syncthreads();
    #pragma unroll
    for (int j = 0; j < A1_ITER; ++j) {
        int d = dc[j];
        if (d >= 0) {
            int e = cbase + j * A1_BLK + tid;
            int b = bucket_of(d);
            int r = atomicAdd(&rk[b], 1);
            int slot = off[b] + r;
            if (!fixed || slot < (b + 1) * CAP)   // overflow guard (never taken)
                ebuf[slot] = ((unsigned)src[e] << 7) | (unsigned)(d - b * NPB);
        }
    }
}

// ---- B1 (R10 version): per-bucket counting sort by (local_dst, src>>12) ----
#define B1_BLK 512
__global__ void __launch_bounds__(B1_BLK) b1_sort(const unsigned* __restrict__ ebuf,
                                                  const int* __restrict__ base,   // exact path
                                                  const int* __restrict__ cnts,   // fixed path
                                                  const int fixed,
                                                  int* __restrict__ csr,
                                                  int* __restrict__ row_beg,
                                                  int* __restrict__ row_end,
                                                  float* __restrict__ norm) {
    __shared__ int hist[NPB * SBIN], cur[NPB * SBIN], psum[B1_BLK];
    const int b = blockIdx.x, tid = threadIdx.x;
    int beg, cnt;
    if (fixed) { beg = b * CAP; cnt = min(cnts[b], CAP); }
    else       { beg = base[b]; cnt = base[b + 1] - beg; }
    const int end = beg + cnt;
    for (int i = tid; i < NPB * SBIN; i += B1_BLK) { hist[i] = 0; cur[i] = 0; }
    __syncthreads();
    for (int i = beg + tid; i < end; i += B1_BLK) {
        unsigned w = ebuf[i];
        int key = (int)(w & 127u) * SBIN + (int)(w >> 19);   // src>>12
        atomicAdd(&hist[key], 1);
    }
    __syncthreads();
    // in-place exclusive scan of 3200 counters: 7-elem chunks + block scan
    {
        int s = 0;
        const int c0 = tid * 7;
        #pragma unroll
        for (int j = 0; j < 7; ++j) {
            int idx = c0 + j;
            if (idx < NPB * SBIN) { int hh = hist[idx]; hist[idx] = s; s += hh; }
        }
        psum[tid] = s;
    }
    __syncthreads();
    for (int off = 1; off < B1_BLK; off <<= 1) {
        int t = (tid >= off) ? psum[tid - off] : 0;
        __syncthreads();
        psum[tid] += t;
        __syncthreads();
    }
    {
        int add = (tid > 0) ? psum[tid - 1] : 0;
        const int c0 = tid * 7;
        #pragma unroll
        for (int j = 0; j < 7; ++j) {
            int idx = c0 + j;
            if (idx < NPB * SBIN) hist[idx] += add;
        }
    }
    __syncthreads();
    if (tid < NPB) {
        int st = hist[tid * SBIN];
        int nx = (tid == NPB - 1) ? cnt : hist[(tid + 1) * SBIN];
        row_beg[b * NPB + tid] = beg + st;
        row_end[b * NPB + tid] = beg + nx;
        norm[b * NPB + tid] = rsqrtf(fmaxf((float)(nx - st), 1.0f));
    }
    __syncthreads();
    for (int i = beg + tid; i < end; i += B1_BLK) {
        unsigned w = ebuf[i];
        int s = (int)(w >> 7);
        int key = (int)(w & 127u) * SBIN + (s >> 12);
        int r = atomicAdd(&cur[key], 1);
        csr[beg + hist[key] + r] = s;
    }
}

// ---- preGEMM via MFMA: g8[n] = fp8(norm[n] * (feat[n] @ W^T)) ---------------
// Byte stores: each wave writes all bytes of its rows' lines within a few
// instructions -> L2 merges them into full-line writebacks.
#define PG_NBLK 512
#define PG_NTILE ((N_NODES + 63) / 64)   // 1563, last tile partial
__global__ void __launch_bounds__(256, 2) pregemm_mfma(const float* __restrict__ feat,
                                                       const float* __restrict__ W,
                                                       const float* __restrict__ norm,
                                                       unsigned char* __restrict__ g8) {
    const int wid = threadIdx.x >> 6;
    const int l   = threadIdx.x & 63;
    const int lr  = l & 15;             // A-row / B-col / C-col
    const int lk  = (l >> 4) * 8;       // k-offset base

    f16x8 bf[8][4];
    #pragma unroll
    for (int nt = 0; nt < 8; ++nt) {
        #pragma unroll
        for (int kb = 0; kb < 4; ++kb) {
            const float* wp = W + (size_t)(nt * 16 + lr) * DIM + kb * 32 + lk;
            float4 w0 = *reinterpret_cast<const float4*>(wp);
            float4 w1 = *reinterpret_cast<const float4*>(wp + 4);
            f16x8 t;
            t[0] = (f16)w0.x; t[1] = (f16)w0.y; t[2] = (f16)w0.z; t[3] = (f16)w0.w;
            t[4] = (f16)w1.x; t[5] = (f16)w1.y; t[6] = (f16)w1.z; t[7] = (f16)w1.w;
            bf[nt][kb] = t;
        }
    }

    for (int tile = blockIdx.x; tile < PG_NTILE; tile += PG_NBLK) {
        const int r0 = tile * 64 + wid * 16;
        if (r0 >= N_NODES) continue;
        f32x4 acc[8] = {};
        #pragma unroll
        for (int kb = 0; kb < 4; ++kb) {
            int ar = r0 + lr;
            if (ar >= N_NODES) ar = N_NODES - 1;
            const float* ap = feat + (size_t)ar * DIM + kb * 32 + lk;
            float4 a0 = *reinterpret_cast<const float4*>(ap);
            float4 a1 = *reinterpret_cast<const float4*>(ap + 4);
            f16x8 a;
            a[0] = (f16)a0.x; a[1] = (f16)a0.y; a[2] = (f16)a0.z; a[3] = (f16)a0.w;
            a[4] = (f16)a1.x; a[5] = (f16)a1.y; a[6] = (f16)a1.z; a[7] = (f16)a1.w;
            #pragma unroll
            for (int nt = 0; nt < 8; ++nt)
                acc[nt] = __builtin_amdgcn_mfma_f32_16x16x32_f16(a, bf[nt][kb], acc[nt], 0, 0, 0);
        }
        const int orow0 = r0 + (l >> 4) * 4;
        float nrm[4];
        #pragma unroll
        for (int j = 0; j < 4; ++j)
            nrm[j] = (orow0 + j < N_NODES) ? norm[orow0 + j] : 0.f;
        #pragma unroll
        for (int nt = 0; nt < 8; ++nt) {
            #pragma unroll
            for (int j = 0; j < 4; ++j) {
                int row = orow0 + j;
                if (row < N_NODES)
                    g8[(size_t)row * DIM + nt * 16 + lr] =
                        f32_to_fp8(acc[nt][j] * nrm[j]);
            }
        }
    }
}

// ---- gather2: one wave per node; fp8 rows (128 B): two rows per load iter ---
// lane = sub*32+li; per load lane reads uint = dims 4li..4li+3 of row
// csr[e+2j+sub]. 8 loads in flight cover 16 edges. XCD-chunked swizzle.
#define G2_NBLK (N_NODES / 4)            // 25000, % 8 == 0 (bijective swizzle)
__global__ void __launch_bounds__(256) gather2(const unsigned char* __restrict__ g8,
                                               const float* __restrict__ norm,
                                               const float* __restrict__ feat,
                                               const int* __restrict__ row_beg,
                                               const int* __restrict__ row_end,
                                               const int* __restrict__ csr,
                                               float* __restrict__ out) {
    const int bswz = (blockIdx.x & 7) * (G2_NBLK / 8) + (blockIdx.x >> 3);
    const int n = bswz * 4 + (threadIdx.x >> 6);
    const int l = threadIdx.x & 63;
    const int sub = l >> 5, li = l & 31;
    const int beg = row_beg[n];
    const int end = row_end[n];
    float a0 = 0.f, a1 = 0.f, a2 = 0.f, a3 = 0.f;
    int e = beg;
    for (; e + 15 < end; e += 16) {      // 8 independent in-flight loads
        int s[8];
        #pragma unroll
        for (int j = 0; j < 8; ++j) s[j] = csr[e + 2 * j + sub];
        unsigned u[8];
        #pragma unroll
        for (int j = 0; j < 8; ++j)
            u[j] = reinterpret_cast<const unsigned*>(g8 + (size_t)s[j] * DIM)[li];
        #pragma unroll
        for (int j = 0; j < 8; ++j) fp8x4_acc(u[j], a0, a1, a2, a3);
    }
    for (; e + 7 < end; e += 8) {
        int s[4];
        #pragma unroll
        for (int j = 0; j < 4; ++j) s[j] = csr[e + 2 * j + sub];
        unsigned u[4];
        #pragma unroll
        for (int j = 0; j < 4; ++j)
            u[j] = reinterpret_cast<const unsigned*>(g8 + (size_t)s[j] * DIM)[li];
        #pragma unroll
        for (int j = 0; j < 4; ++j) fp8x4_acc(u[j], a0, a1, a2, a3);
    }
    for (; e + 1 < end; e += 2) {
        const int s = csr[e + sub];
        unsigned u = reinterpret_cast<const unsigned*>(g8 + (size_t)s * DIM)[li];
        fp8x4_acc(u, a0, a1, a2, a3);
    }
    if (e < end) {                       // odd leftover: half 0 only
        const int s = csr[e];
        unsigned u = reinterpret_cast<const unsigned*>(g8 + (size_t)s * DIM)[li];
        if (sub == 0) fp8x4_acc(u, a0, a1, a2, a3);
    }
    // combine the two half-wave partials
    a0 += __shfl_xor(a0, 32);
    a1 += __shfl_xor(a1, 32);
    a2 += __shfl_xor(a2, 32);
    a3 += __shfl_xor(a3, 32);
    if (sub == 0) {
        const float nm = norm[n];
        const float4 f = reinterpret_cast<const float4*>(feat + (size_t)n * DIM)[li];
        float4 o;
        o.x = fmaxf(a0 * nm, 0.f) + f.x;
        o.y = fmaxf(a1 * nm, 0.f) + f.y;
        o.z = fmaxf(a2 * nm, 0.f) + f.z;
        o.w = fmaxf(a3 * nm, 0.f) + f.w;
        reinterpret_cast<float4*>(out + (size_t)n * DIM)[li] = o;
    }
}

// ============================ FALLBACK (round-2 path) =======================
#define SCAN_B 1024
#define N_SCANB ((N_NODES + SCAN_B - 1) / SCAN_B)

__global__ void __launch_bounds__(256) deg_kernel(const int* __restrict__ dst,
                                                  int* __restrict__ deg) {
    int i = blockIdx.x * 256 + threadIdx.x;
    if (i < N_EDGES) atomicAdd(&deg[dst[i]], 1);
}
__global__ void __launch_bounds__(SCAN_B) scan1_kernel(const int* __restrict__ deg,
                                                       int* __restrict__ excl,
                                                       int* __restrict__ partials) {
    __shared__ int buf[SCAN_B];
    const int gid = blockIdx.x * SCAN_B + threadIdx.x;
    const int v = (gid < N_NODES) ? deg[gid] : 0;
    buf[threadIdx.x] = v;
    __syncthreads();
    #pragma unroll
    for (int off = 1; off < SCAN_B; off <<= 1) {
        int t = (threadIdx.x >= off) ? buf[threadIdx.x - off] : 0;
        __syncthreads();
        buf[threadIdx.x] += t;
        __syncthreads();
    }
    if (gid < N_NODES) excl[gid] = buf[threadIdx.x] - v;
    if (threadIdx.x == SCAN_B - 1) partials[blockIdx.x] = buf[threadIdx.x];
}
__global__ void __launch_bounds__(128) scan2_kernel(int* __restrict__ partials) {
    __shared__ int buf[128];
    const int v = (threadIdx.x < N_SCANB) ? partials[threadIdx.x] : 0;
    buf[threadIdx.x] = v;
    __syncthreads();
    #pragma unroll
    for (int off = 1; off < 128; off <<= 1) {
        int t = (threadIdx.x >= off) ? buf[threadIdx.x - off] : 0;
        __syncthreads();
        buf[threadIdx.x] += t;
        __syncthreads();
    }
    if (threadIdx.x < N_SCANB) partials[threadIdx.x] = buf[threadIdx.x] - v;
}
__global__ void __launch_bounds__(SCAN_B) scan3_kernel(
        const int* __restrict__ excl, const int* __restrict__ partials,
        const int* __restrict__ deg,
        int* __restrict__ row_start, int* __restrict__ cursor,
        float* __restrict__ norm) {
    const int gid = blockIdx.x * SCAN_B + threadIdx.x;
    if (gid < N_NODES) {
        const int rs = excl[gid] + partials[blockIdx.x];
        row_start[gid] = rs;
        cursor[gid] = rs;
        norm[gid] = rsqrtf(fmaxf((float)deg[gid], 1.0f));
    }
    if (gid == 0) row_start[N_NODES] = N_EDGES;
}
__global__ void __launch_bounds__(256) fill_kernel(
        const int* __restrict__ src, const int* __restrict__ dst,
        int* __restrict__ cursor, int* __restrict__ csr) {
    int i = blockIdx.x * 256 + threadIdx.x;
    if (i < N_EDGES) {
        int pos = atomicAdd(&cursor[dst[i]], 1);
        csr[pos] = src[i];
    }
}
__global__ void __launch_bounds__(256) gather_kernel(
        const float* __restrict__ feat, const float* __restrict__ norm,
        const int* __restrict__ row_start, const int* __restrict__ csr,
        float* __restrict__ out) {
    const int n = blockIdx.x * 4 + (threadIdx.x >> 6);
    if (n >= N_NODES) return;
    const int lane = threadIdx.x & 63;
    const int beg = row_start[n];
    const int end = row_start[n + 1];
    float2 acc = make_float2(0.f, 0.f);
    int e = beg;
    for (; e + 1 < end; e += 2) {
        const int s0 = csr[e], s1 = csr[e + 1];
        const float w0 = norm[s0], w1 = norm[s1];
        const float2 v0 = reinterpret_cast<const float2*>(feat + (size_t)s0 * DIM)[lane];
        const float2 v1 = reinterpret_cast<const float2*>(feat + (size_t)s1 * DIM)[lane];
        acc.x = fmaf(v0.x, w0, acc.x); acc.y = fmaf(v0.y, w0, acc.y);
        acc.x = fmaf(v1.x, w1, acc.x); acc.y = fmaf(v1.y, w1, acc.y);
    }
    if (e < end) {
        const int s0 = csr[e];
        const float w0 = norm[s0];
        const float2 v0 = reinterpret_cast<const float2*>(feat + (size_t)s0 * DIM)[lane];
        acc.x = fmaf(v0.x, w0, acc.x); acc.y = fmaf(v0.y, w0, acc.y);
    }
    reinterpret_cast<float2*>(out + (size_t)n * DIM)[lane] = acc;
}
__global__ void __launch_bounds__(256) final_kernel(
        const float* __restrict__ feat, const float* __restrict__ W,
        const float* __restrict__ norm, float* __restrict__ out) {
    __shared__ float Wt[DIM * DIM];
    __shared__ float rowbuf[8][DIM];
    for (int idx = threadIdx.x; idx < DIM * DIM; idx += 256)
        Wt[idx] = W[(idx & 127) * DIM + (idx >> 7)];
    const int o  = threadIdx.x & 127;
    const int r0 = (threadIdx.x >> 7) * 4;
    for (int rb = blockIdx.x * 8; rb < N_NODES; rb += gridDim.x * 8) {
        __syncthreads();
        float4 v = reinterpret_cast<const float4*>(out + (size_t)rb * DIM)[threadIdx.x];
        reinterpret_cast<float4*>(&rowbuf[0][0])[threadIdx.x] = v;
        __syncthreads();
        float acc0 = 0.f, acc1 = 0.f, acc2 = 0.f, acc3 = 0.f;
        #pragma unroll 8
        for (int k = 0; k < DIM; ++k) {
            float w = Wt[k * DIM + o];
            acc0 = fmaf(rowbuf[r0 + 0][k], w, acc0);
            acc1 = fmaf(rowbuf[r0 + 1][k], w, acc1);
            acc2 = fmaf(rowbuf[r0 + 2][k], w, acc2);
            acc3 = fmaf(rowbuf[r0 + 3][k], w, acc3);
        }
        float accs[4] = {acc0, acc1, acc2, acc3};
        #pragma unroll
        for (int r = 0; r < 4; ++r) {
            int row = rb + r0 + r;
            float val = fmaxf(accs[r] * norm[row], 0.0f) + feat[(size_t)row * DIM + o];
            out[(size_t)row * DIM + o] = val;
        }
    }
}

// ============================ launch ========================================
extern "C" void kernel_launch(void* const* d_in, const int* in_sizes, int n_in,
                              void* d_out, int out_size, void* d_ws, size_t ws_size,
                              hipStream_t stream) {
    const float* feat = (const float*)d_in[0];
    const float* W    = (const float*)d_in[1];
    const int*   src  = (const int*)d_in[2];
    const int*   dst  = (const int*)d_in[3];
    float* out = (float*)d_out;

    const size_t G8_BYTES   = (size_t)N_NODES * DIM;          // 12.8 MB
    const size_t EBUF_FIX   = (size_t)NB * CAP * 4;           // 15.36 MB
    const size_t EBUF_EXACT = (size_t)N_EDGES * 4;            // 12.8 MB
    const int    A1_GRID    = (N_EDGES + A1_CHUNK - 1) / A1_CHUNK;   // 196

    // ---- fast path (fixed-capacity buckets), ~32 MB ----
    {
        char* p = (char*)d_ws;
        unsigned char* g8 = (unsigned char*)p;
        unsigned* ebuf  = (unsigned*)p; p += (G8_BYTES > EBUF_FIX ? G8_BYTES : EBUF_FIX);
        int*      csr   = (int*)p;      p += EBUF_FIX;
        float*    norm  = (float*)p;    p += (size_t)N_NODES * 4;
        int*   row_beg  = (int*)p;      p += (size_t)N_NODES * 4;
        int*   row_end  = (int*)p;      p += (size_t)N_NODES * 4;
        int*   cursor   = (int*)p;      p += NB * 4;
        if (ws_size >= (size_t)(p - (char*)d_ws)) {
            hipMemsetAsync(cursor, 0, NB * sizeof(int), stream);
            a1_fill     <<<A1_GRID, A1_BLK, 0, stream>>>(src, dst, cursor, ebuf, 1);
            b1_sort     <<<NB, B1_BLK, 0, stream>>>(ebuf, nullptr, cursor, 1, csr, row_beg, row_end, norm);
            pregemm_mfma<<<PG_NBLK, 256, 0, stream>>>(feat, W, norm, g8);   // overwrites ebuf
            gather2     <<<G2_NBLK, 256, 0, stream>>>(g8, norm, feat, row_beg, row_end, csr, out);
            return;
        }
    }

    // ---- middle path (exact bases via a0+bscan), ~28 MB ----
    {
        char* p = (char*)d_ws;
        unsigned char* g8 = (unsigned char*)p;
        unsigned* ebuf  = (unsigned*)p; p += (G8_BYTES > EBUF_EXACT ? G8_BYTES : EBUF_EXACT);
        int*      csr   = (int*)p;      p += EBUF_EXACT;
        float*    norm  = (float*)p;    p += (size_t)N_NODES * 4;
        int*   row_beg  = (int*)p;      p += (size_t)N_NODES * 4;
        int*   row_end  = (int*)p;      p += (size_t)N_NODES * 4;
        int*      ghist = (int*)p;      p += NB * 4;
        int*      bbase = (int*)p;      p += (NB + 4) * 4;
        int*      bcur  = (int*)p;      p += NB * 4;
        if (ws_size >= (size_t)(p - (char*)d_ws)) {
            hipMemsetAsync(ghist, 0, NB * sizeof(int), stream);
            a0_hist     <<<(N_EDGES + 4095) / 4096, 256, 0, stream>>>(dst, ghist);
            bscan_kernel<<<1, 1024, 0, stream>>>(ghist, bbase, bcur);
            a1_fill     <<<A1_GRID, A1_BLK, 0, stream>>>(src, dst, bcur, ebuf, 0);
            b1_sort     <<<NB, B1_BLK, 0, stream>>>(ebuf, bbase, nullptr, 0, csr, row_beg, row_end, norm);
            pregemm_mfma<<<PG_NBLK, 256, 0, stream>>>(feat, W, norm, g8);
            gather2     <<<G2_NBLK, 256, 0, stream>>>(g8, norm, feat, row_beg, row_end, csr, out);
            return;
        }
    }

    // ---- last-resort fallback (round-2 path, ~14.8 MB) ----
    {
        char* q = (char*)d_ws;
        int*   deg       = (int*)q;   q += N_NODES * sizeof(int);
        int*   excl      = (int*)q;   q += N_NODES * sizeof(int);
        int*   cursor    = (int*)q;   q += N_NODES * sizeof(int);
        int*   row_start2= (int*)q;   q += (N_NODES + 1) * sizeof(int);
        float* nrm       = (float*)q; q += N_NODES * sizeof(float);
        int*   partials  = (int*)q;   q += 128 * sizeof(int);
        int*   csr2      = (int*)q;

        hipMemsetAsync(deg, 0, (size_t)N_NODES * sizeof(int), stream);
        deg_kernel  <<<N_EDGES / 256, 256, 0, stream>>>(dst, deg);
        scan1_kernel<<<N_SCANB, SCAN_B, 0, stream>>>(deg, excl, partials);
        scan2_kernel<<<1, 128, 0, stream>>>(partials);
        scan3_kernel<<<N_SCANB, SCAN_B, 0, stream>>>(excl, partials, deg,
                                                     row_start2, cursor, nrm);
        fill_kernel <<<N_EDGES / 256, 256, 0, stream>>>(src, dst, cursor, csr2);
        gather_kernel<<<(N_NODES + 3) / 4, 256, 0, stream>>>(feat, nrm, row_start2, csr2, out);
        final_kernel<<<512, 256, 0, stream>>>(feat, W, nrm, out);
    }
}

// Round 13
// 163.211 us; speedup vs baseline: 1.3387x; 1.0295x over previous
//
#include <hip/hip_runtime.h>
#include <hip/hip_fp16.h>
#include <hip/hip_fp8.h>

#define N_NODES 100000
#define N_EDGES 3200000
#define DIM 128
#define NB 1000        // dst buckets
#define NPB 100        // nodes per bucket (NB*NPB == N_NODES exactly)
#define CAP 3840       // fixed slots per bucket: mean 3200, sigma ~57 -> +11.3 sigma
#define SBIN 32        // coarse src bins per node (src>>12 -> 0..24); 1 MB window

typedef _Float16 f16;
typedef f16 f16x8 __attribute__((ext_vector_type(8)));
typedef float f32x4 __attribute__((ext_vector_type(4)));
typedef float f32x2 __attribute__((ext_vector_type(2)));

// dst/100 via magic multiply (exact for dst < 2^30)
__device__ __forceinline__ int bucket_of(int dst) {
    return (int)(((unsigned long long)(unsigned)dst * 42949673ull) >> 32);
}

// ---- fp8 e4m3 (OCP on gfx950) encode/decode, HW cvt with header fallback ----
__device__ __forceinline__ unsigned char f32_to_fp8(float x) {
#if __has_builtin(__builtin_amdgcn_cvt_pk_fp8_f32)
    int r = __builtin_amdgcn_cvt_pk_fp8_f32(x, x, 0, false);
    return (unsigned char)(r & 0xff);
#else
    __hip_fp8_e4m3 q(x);
    return (unsigned char)q.__x;
#endif
}
__device__ __forceinline__ void fp8x4_acc(unsigned u, float& a0, float& a1,
                                          float& a2, float& a3) {
#if __has_builtin(__builtin_amdgcn_cvt_pk_f32_fp8)
    f32x2 lo = __builtin_amdgcn_cvt_pk_f32_fp8((int)u, false);
    f32x2 hi = __builtin_amdgcn_cvt_pk_f32_fp8((int)u, true);
    a0 += lo[0]; a1 += lo[1]; a2 += hi[0]; a3 += hi[1];
#else
    __hip_fp8_e4m3 q0, q1, q2, q3;
    q0.__x = (unsigned char)(u & 0xffu);
    q1.__x = (unsigned char)((u >> 8) & 0xffu);
    q2.__x = (unsigned char)((u >> 16) & 0xffu);
    q3.__x = (unsigned char)((u >> 24) & 0xffu);
    a0 += (float)q0; a1 += (float)q1; a2 += (float)q2; a3 += (float)q3;
#endif
}

// ---- A0 (middle path only): global per-bucket edge counts ----
__global__ void __launch_bounds__(256) a0_hist(const int* __restrict__ dst,
                                               int* __restrict__ ghist) {
    __shared__ int h[NB];
    for (int i = threadIdx.x; i < NB; i += 256) h[i] = 0;
    __syncthreads();
    const int base = blockIdx.x * 4096 + threadIdx.x;
    #pragma unroll
    for (int i = 0; i < 16; ++i) {
        int e = base + i * 256;
        if (e < N_EDGES) atomicAdd(&h[bucket_of(dst[e])], 1);
    }
    __syncthreads();
    for (int i = threadIdx.x; i < NB; i += 256)
        if (h[i]) atomicAdd(&ghist[i], h[i]);
}

// ---- scan of 1000 bucket counts -> base[], cursor[] (middle path only) ----
__global__ void __launch_bounds__(1024) bscan_kernel(const int* __restrict__ ghist,
                                                     int* __restrict__ base,
                                                     int* __restrict__ cursor) {
    __shared__ int buf[1024];
    const int v = (threadIdx.x < NB) ? ghist[threadIdx.x] : 0;
    buf[threadIdx.x] = v;
    __syncthreads();
    for (int off = 1; off < 1024; off <<= 1) {
        int t = (threadIdx.x >= off) ? buf[threadIdx.x - off] : 0;
        __syncthreads();
        buf[threadIdx.x] += t;
        __syncthreads();
    }
    if (threadIdx.x < NB) {
        int excl = buf[threadIdx.x] - v;
        base[threadIdx.x] = excl;
        cursor[threadIdx.x] = excl;
    }
    if (threadIdx.x == NB - 1) base[NB] = buf[threadIdx.x];
}

// ---- A1 (R10 version): 16384-edge chunks, 1024-thread blocks ----
#define A1_CHUNK 16384
#define A1_BLK 1024
#define A1_ITER (A1_CHUNK / A1_BLK)   // 16
__global__ void __launch_bounds__(A1_BLK) a1_fill(const int* __restrict__ src,
                                                  const int* __restrict__ dst,
                                                  int* __restrict__ cursor,
                                                  unsigned* __restrict__ ebuf,
                                                  const int fixed) {
    __shared__ int h[NB], off[NB], rk[NB];
    const int tid = threadIdx.x;
    for (int i = tid; i < NB; i += A1_BLK) { h[i] = 0; rk[i] = 0; }
    __syncthreads();
    const int cbase = blockIdx.x * A1_CHUNK;
    int dc[A1_ITER];
    #pragma unroll
    for (int j = 0; j < A1_ITER; ++j) {
        int e = cbase + j * A1_BLK + tid;
        int d = (e < N_EDGES) ? dst[e] : -1;
        dc[j] = d;
        if (d >= 0) atomicAdd(&h[bucket_of(d)], 1);
    }
    __syncthreads();
    for (int i = tid; i < NB; i += A1_BLK) {
        int c = h[i];
        int o = c ? atomicAdd(&cursor[i], c) : 0;
        off[i] = (fixed ? i * CAP : 0) + o;
    }
    __syncthreads();
    #pragma unroll
    for (int j = 0; j < A1_ITER; ++j) {
        int d = dc[j];
        if (d >= 0) {
            int e = cbase + j * A1_BLK + tid;
            int b = bucket_of(d);
            int r = atomicAdd(&rk[b], 1);
            int slot = off[b] + r;
            if (!fixed || slot < (b + 1) * CAP)   // overflow guard (never taken)
                ebuf[slot] = ((unsigned)src[e] << 7) | (unsigned)(d - b * NPB);
        }
    }
}

// ---- B1: per-bucket counting sort by (local_dst, src>>12) ------------------
// Place pass scatters into LDS sorted[] (banked, scatter-tolerant); copy-out
// to csr is fully coalesced 512-thread streaming -> ~16x fewer write txns.
#define B1_BLK 512
__global__ void __launch_bounds__(B1_BLK) b1_sort(const unsigned* __restrict__ ebuf,
                                                  const int* __restrict__ base,   // exact path
                                                  const int* __restrict__ cnts,   // fixed path
                                                  const int fixed,
                                                  int* __restrict__ csr,
                                                  int* __restrict__ row_beg,
                                                  int* __restrict__ row_end,
                                                  float* __restrict__ norm) {
    __shared__ int hist[NPB * SBIN], cur[NPB * SBIN], psum[B1_BLK];
    __shared__ int sorted[CAP];                    // 15.4 KB staging
    const int b = blockIdx.x, tid = threadIdx.x;
    int beg, cnt;
    if (fixed) { beg = b * CAP; cnt = min(cnts[b], CAP); }
    else       { beg = base[b]; cnt = base[b + 1] - beg; }
    const int end = beg + cnt;
    for (int i = tid; i < NPB * SBIN; i += B1_BLK) { hist[i] = 0; cur[i] = 0; }
    __syncthreads();
    for (int i = beg + tid; i < end; i += B1_BLK) {
        unsigned w = ebuf[i];
        int key = (int)(w & 127u) * SBIN + (int)(w >> 19);   // src>>12
        atomicAdd(&hist[key], 1);
    }
    __syncthreads();
    // in-place exclusive scan of 3200 counters: 7-elem chunks + block scan
    {
        int s = 0;
        const int c0 = tid * 7;
        #pragma unroll
        for (int j = 0; j < 7; ++j) {
            int idx = c0 + j;
            if (idx < NPB * SBIN) { int hh = hist[idx]; hist[idx] = s; s += hh; }
        }
        psum[tid] = s;
    }
    __syncthreads();
    for (int off = 1; off < B1_BLK; off <<= 1) {
        int t = (tid >= off) ? psum[tid - off] : 0;
        __syncthreads();
        psum[tid] += t;
        __syncthreads();
    }
    {
        int add = (tid > 0) ? psum[tid - 1] : 0;
        const int c0 = tid * 7;
        #pragma unroll
        for (int j = 0; j < 7; ++j) {
            int idx = c0 + j;
            if (idx < NPB * SBIN) hist[idx] += add;
        }
    }
    __syncthreads();
    if (tid < NPB) {
        int st = hist[tid * SBIN];
        int nx = (tid == NPB - 1) ? cnt : hist[(tid + 1) * SBIN];
        row_beg[b * NPB + tid] = beg + st;
        row_end[b * NPB + tid] = beg + nx;
        norm[b * NPB + tid] = rsqrtf(fmaxf((float)(nx - st), 1.0f));
    }
    __syncthreads();
    if (cnt <= CAP) {
        // scatter into LDS (cheap), then coalesced copy-out
        for (int i = beg + tid; i < end; i += B1_BLK) {
            unsigned w = ebuf[i];
            int s = (int)(w >> 7);
            int key = (int)(w & 127u) * SBIN + (s >> 12);
            int r = atomicAdd(&cur[key], 1);
            sorted[hist[key] + r] = s;
        }
        __syncthreads();
        for (int i = tid; i < cnt; i += B1_BLK) csr[beg + i] = sorted[i];
    } else {
        // middle-path safety: direct global scatter
        for (int i = beg + tid; i < end; i += B1_BLK) {
            unsigned w = ebuf[i];
            int s = (int)(w >> 7);
            int key = (int)(w & 127u) * SBIN + (s >> 12);
            int r = atomicAdd(&cur[key], 1);
            csr[beg + hist[key] + r] = s;
        }
    }
}

// ---- preGEMM via MFMA: g8[n] = fp8(norm[n] * (feat[n] @ W^T)) ---------------
#define PG_NBLK 512
#define PG_NTILE ((N_NODES + 63) / 64)   // 1563, last tile partial
__global__ void __launch_bounds__(256, 2) pregemm_mfma(const float* __restrict__ feat,
                                                       const float* __restrict__ W,
                                                       const float* __restrict__ norm,
                                                       unsigned char* __restrict__ g8) {
    const int wid = threadIdx.x >> 6;
    const int l   = threadIdx.x & 63;
    const int lr  = l & 15;             // A-row / B-col / C-col
    const int lk  = (l >> 4) * 8;       // k-offset base

    f16x8 bf[8][4];
    #pragma unroll
    for (int nt = 0; nt < 8; ++nt) {
        #pragma unroll
        for (int kb = 0; kb < 4; ++kb) {
            const float* wp = W + (size_t)(nt * 16 + lr) * DIM + kb * 32 + lk;
            float4 w0 = *reinterpret_cast<const float4*>(wp);
            float4 w1 = *reinterpret_cast<const float4*>(wp + 4);
            f16x8 t;
            t[0] = (f16)w0.x; t[1] = (f16)w0.y; t[2] = (f16)w0.z; t[3] = (f16)w0.w;
            t[4] = (f16)w1.x; t[5] = (f16)w1.y; t[6] = (f16)w1.z; t[7] = (f16)w1.w;
            bf[nt][kb] = t;
        }
    }

    for (int tile = blockIdx.x; tile < PG_NTILE; tile += PG_NBLK) {
        const int r0 = tile * 64 + wid * 16;
        if (r0 >= N_NODES) continue;
        f32x4 acc[8] = {};
        #pragma unroll
        for (int kb = 0; kb < 4; ++kb) {
            int ar = r0 + lr;
            if (ar >= N_NODES) ar = N_NODES - 1;
            const float* ap = feat + (size_t)ar * DIM + kb * 32 + lk;
            float4 a0 = *reinterpret_cast<const float4*>(ap);
            float4 a1 = *reinterpret_cast<const float4*>(ap + 4);
            f16x8 a;
            a[0] = (f16)a0.x; a[1] = (f16)a0.y; a[2] = (f16)a0.z; a[3] = (f16)a0.w;
            a[4] = (f16)a1.x; a[5] = (f16)a1.y; a[6] = (f16)a1.z; a[7] = (f16)a1.w;
            #pragma unroll
            for (int nt = 0; nt < 8; ++nt)
                acc[nt] = __builtin_amdgcn_mfma_f32_16x16x32_f16(a, bf[nt][kb], acc[nt], 0, 0, 0);
        }
        const int orow0 = r0 + (l >> 4) * 4;
        float nrm[4];
        #pragma unroll
        for (int j = 0; j < 4; ++j)
            nrm[j] = (orow0 + j < N_NODES) ? norm[orow0 + j] : 0.f;
        #pragma unroll
        for (int nt = 0; nt < 8; ++nt) {
            #pragma unroll
            for (int j = 0; j < 4; ++j) {
                int row = orow0 + j;
                if (row < N_NODES)
                    g8[(size_t)row * DIM + nt * 16 + lr] =
                        f32_to_fp8(acc[nt][j] * nrm[j]);
            }
        }
    }
}

// ---- gather2: one wave per node; fp8 rows (128 B); 8 loads in flight --------
#define G2_NBLK (N_NODES / 4)            // 25000, % 8 == 0 (bijective swizzle)
__global__ void __launch_bounds__(256) gather2(const unsigned char* __restrict__ g8,
                                               const float* __restrict__ norm,
                                               const float* __restrict__ feat,
                                               const int* __restrict__ row_beg,
                                               const int* __restrict__ row_end,
                                               const int* __restrict__ csr,
                                               float* __restrict__ out) {
    const int bswz = (blockIdx.x & 7) * (G2_NBLK / 8) + (blockIdx.x >> 3);
    const int n = bswz * 4 + (threadIdx.x >> 6);
    const int l = threadIdx.x & 63;
    const int sub = l >> 5, li = l & 31;
    const int beg = row_beg[n];
    const int end = row_end[n];
    float a0 = 0.f, a1 = 0.f, a2 = 0.f, a3 = 0.f;
    int e = beg;
    for (; e + 15 < end; e += 16) {      // 8 independent in-flight loads
        int s[8];
        #pragma unroll
        for (int j = 0; j < 8; ++j) s[j] = csr[e + 2 * j + sub];
        unsigned u[8];
        #pragma unroll
        for (int j = 0; j < 8; ++j)
            u[j] = reinterpret_cast<const unsigned*>(g8 + (size_t)s[j] * DIM)[li];
        #pragma unroll
        for (int j = 0; j < 8; ++j) fp8x4_acc(u[j], a0, a1, a2, a3);
    }
    for (; e + 7 < end; e += 8) {
        int s[4];
        #pragma unroll
        for (int j = 0; j < 4; ++j) s[j] = csr[e + 2 * j + sub];
        unsigned u[4];
        #pragma unroll
        for (int j = 0; j < 4; ++j)
            u[j] = reinterpret_cast<const unsigned*>(g8 + (size_t)s[j] * DIM)[li];
        #pragma unroll
        for (int j = 0; j < 4; ++j) fp8x4_acc(u[j], a0, a1, a2, a3);
    }
    for (; e + 1 < end; e += 2) {
        const int s = csr[e + sub];
        unsigned u = reinterpret_cast<const unsigned*>(g8 + (size_t)s * DIM)[li];
        fp8x4_acc(u, a0, a1, a2, a3);
    }
    if (e < end) {                       // odd leftover: half 0 only
        const int s = csr[e];
        unsigned u = reinterpret_cast<const unsigned*>(g8 + (size_t)s * DIM)[li];
        if (sub == 0) fp8x4_acc(u, a0, a1, a2, a3);
    }
    // combine the two half-wave partials
    a0 += __shfl_xor(a0, 32);
    a1 += __shfl_xor(a1, 32);
    a2 += __shfl_xor(a2, 32);
    a3 += __shfl_xor(a3, 32);
    if (sub == 0) {
        const float nm = norm[n];
        const float4 f = reinterpret_cast<const float4*>(feat + (size_t)n * DIM)[li];
        float4 o;
        o.x = fmaxf(a0 * nm, 0.f) + f.x;
        o.y = fmaxf(a1 * nm, 0.f) + f.y;
        o.z = fmaxf(a2 * nm, 0.f) + f.z;
        o.w = fmaxf(a3 * nm, 0.f) + f.w;
        reinterpret_cast<float4*>(out + (size_t)n * DIM)[li] = o;
    }
}

// ============================ FALLBACK (round-2 path) =======================
#define SCAN_B 1024
#define N_SCANB ((N_NODES + SCAN_B - 1) / SCAN_B)

__global__ void __launch_bounds__(256) deg_kernel(const int* __restrict__ dst,
                                                  int* __restrict__ deg) {
    int i = blockIdx.x * 256 + threadIdx.x;
    if (i < N_EDGES) atomicAdd(&deg[dst[i]], 1);
}
__global__ void __launch_bounds__(SCAN_B) scan1_kernel(const int* __restrict__ deg,
                                                       int* __restrict__ excl,
                                                       int* __restrict__ partials) {
    __shared__ int buf[SCAN_B];
    const int gid = blockIdx.x * SCAN_B + threadIdx.x;
    const int v = (gid < N_NODES) ? deg[gid] : 0;
    buf[threadIdx.x] = v;
    __syncthreads();
    #pragma unroll
    for (int off = 1; off < SCAN_B; off <<= 1) {
        int t = (threadIdx.x >= off) ? buf[threadIdx.x - off] : 0;
        __syncthreads();
        buf[threadIdx.x] += t;
        __syncthreads();
    }
    if (gid < N_NODES) excl[gid] = buf[threadIdx.x] - v;
    if (threadIdx.x == SCAN_B - 1) partials[blockIdx.x] = buf[threadIdx.x];
}
__global__ void __launch_bounds__(128) scan2_kernel(int* __restrict__ partials) {
    __shared__ int buf[128];
    const int v = (threadIdx.x < N_SCANB) ? partials[threadIdx.x] : 0;
    buf[threadIdx.x] = v;
    __syncthreads();
    #pragma unroll
    for (int off = 1; off < 128; off <<= 1) {
        int t = (threadIdx.x >= off) ? buf[threadIdx.x - off] : 0;
        __syncthreads();
        buf[threadIdx.x] += t;
        __syncthreads();
    }
    if (threadIdx.x < N_SCANB) partials[threadIdx.x] = buf[threadIdx.x] - v;
}
__global__ void __launch_bounds__(SCAN_B) scan3_kernel(
        const int* __restrict__ excl, const int* __restrict__ partials,
        const int* __restrict__ deg,
        int* __restrict__ row_start, int* __restrict__ cursor,
        float* __restrict__ norm) {
    const int gid = blockIdx.x * SCAN_B + threadIdx.x;
    if (gid < N_NODES) {
        const int rs = excl[gid] + partials[blockIdx.x];
        row_start[gid] = rs;
        cursor[gid] = rs;
        norm[gid] = rsqrtf(fmaxf((float)deg[gid], 1.0f));
    }
    if (gid == 0) row_start[N_NODES] = N_EDGES;
}
__global__ void __launch_bounds__(256) fill_kernel(
        const int* __restrict__ src, const int* __restrict__ dst,
        int* __restrict__ cursor, int* __restrict__ csr) {
    int i = blockIdx.x * 256 + threadIdx.x;
    if (i < N_EDGES) {
        int pos = atomicAdd(&cursor[dst[i]], 1);
        csr[pos] = src[i];
    }
}
__global__ void __launch_bounds__(256) gather_kernel(
        const float* __restrict__ feat, const float* __restrict__ norm,
        const int* __restrict__ row_start, const int* __restrict__ csr,
        float* __restrict__ out) {
    const int n = blockIdx.x * 4 + (threadIdx.x >> 6);
    if (n >= N_NODES) return;
    const int lane = threadIdx.x & 63;
    const int beg = row_start[n];
    const int end = row_start[n + 1];
    float2 acc = make_float2(0.f, 0.f);
    int e = beg;
    for (; e + 1 < end; e += 2) {
        const int s0 = csr[e], s1 = csr[e + 1];
        const float w0 = norm[s0], w1 = norm[s1];
        const float2 v0 = reinterpret_cast<const float2*>(feat + (size_t)s0 * DIM)[lane];
        const float2 v1 = reinterpret_cast<const float2*>(feat + (size_t)s1 * DIM)[lane];
        acc.x = fmaf(v0.x, w0, acc.x); acc.y = fmaf(v0.y, w0, acc.y);
        acc.x = fmaf(v1.x, w1, acc.x); acc.y = fmaf(v1.y, w1, acc.y);
    }
    if (e < end) {
        const int s0 = csr[e];
        const float w0 = norm[s0];
        const float2 v0 = reinterpret_cast<const float2*>(feat + (size_t)s0 * DIM)[lane];
        acc.x = fmaf(v0.x, w0, acc.x); acc.y = fmaf(v0.y, w0, acc.y);
    }
    reinterpret_cast<float2*>(out + (size_t)n * DIM)[lane] = acc;
}
__global__ void __launch_bounds__(256) final_kernel(
        const float* __restrict__ feat, const float* __restrict__ W,
        const float* __restrict__ norm, float* __restrict__ out) {
    __shared__ float Wt[DIM * DIM];
    __shared__ float rowbuf[8][DIM];
    for (int idx = threadIdx.x; idx < DIM * DIM; idx += 256)
        Wt[idx] = W[(idx & 127) * DIM + (idx >> 7)];
    const int o  = threadIdx.x & 127;
    const int r0 = (threadIdx.x >> 7) * 4;
    for (int rb = blockIdx.x * 8; rb < N_NODES; rb += gridDim.x * 8) {
        __syncthreads();
        float4 v = reinterpret_cast<const float4*>(out + (size_t)rb * DIM)[threadIdx.x];
        reinterpret_cast<float4*>(&rowbuf[0][0])[threadIdx.x] = v;
        __syncthreads();
        float acc0 = 0.f, acc1 = 0.f, acc2 = 0.f, acc3 = 0.f;
        #pragma unroll 8
        for (int k = 0; k < DIM; ++k) {
            float w = Wt[k * DIM + o];
            acc0 = fmaf(rowbuf[r0 + 0][k], w, acc0);
            acc1 = fmaf(rowbuf[r0 + 1][k], w, acc1);
            acc2 = fmaf(rowbuf[r0 + 2][k], w, acc2);
            acc3 = fmaf(rowbuf[r0 + 3][k], w, acc3);
        }
        float accs[4] = {acc0, acc1, acc2, acc3};
        #pragma unroll
        for (int r = 0; r < 4; ++r) {
            int row = rb + r0 + r;
            float val = fmaxf(accs[r] * norm[row], 0.0f) + feat[(size_t)row * DIM + o];
            out[(size_t)row * DIM + o] = val;
        }
    }
}

// ============================ launch ========================================
extern "C" void kernel_launch(void* const* d_in, const int* in_sizes, int n_in,
                              void* d_out, int out_size, void* d_ws, size_t ws_size,
                              hipStream_t stream) {
    const float* feat = (const float*)d_in[0];
    const float* W    = (const float*)d_in[1];
    const int*   src  = (const int*)d_in[2];
    const int*   dst  = (const int*)d_in[3];
    float* out = (float*)d_out;

    const size_t G8_BYTES   = (size_t)N_NODES * DIM;          // 12.8 MB
    const size_t EBUF_FIX   = (size_t)NB * CAP * 4;           // 15.36 MB
    const size_t EBUF_EXACT = (size_t)N_EDGES * 4;            // 12.8 MB
    const int    A1_GRID    = (N_EDGES + A1_CHUNK - 1) / A1_CHUNK;   // 196

    // ---- fast path (fixed-capacity buckets), ~32 MB ----
    {
        char* p = (char*)d_ws;
        unsigned char* g8 = (unsigned char*)p;
        unsigned* ebuf  = (unsigned*)p; p += (G8_BYTES > EBUF_FIX ? G8_BYTES : EBUF_FIX);
        int*      csr   = (int*)p;      p += EBUF_FIX;
        float*    norm  = (float*)p;    p += (size_t)N_NODES * 4;
        int*   row_beg  = (int*)p;      p += (size_t)N_NODES * 4;
        int*   row_end  = (int*)p;      p += (size_t)N_NODES * 4;
        int*   cursor   = (int*)p;      p += NB * 4;
        if (ws_size >= (size_t)(p - (char*)d_ws)) {
            hipMemsetAsync(cursor, 0, NB * sizeof(int), stream);
            a1_fill     <<<A1_GRID, A1_BLK, 0, stream>>>(src, dst, cursor, ebuf, 1);
            b1_sort     <<<NB, B1_BLK, 0, stream>>>(ebuf, nullptr, cursor, 1, csr, row_beg, row_end, norm);
            pregemm_mfma<<<PG_NBLK, 256, 0, stream>>>(feat, W, norm, g8);   // overwrites ebuf
            gather2     <<<G2_NBLK, 256, 0, stream>>>(g8, norm, feat, row_beg, row_end, csr, out);
            return;
        }
    }

    // ---- middle path (exact bases via a0+bscan), ~28 MB ----
    {
        char* p = (char*)d_ws;
        unsigned char* g8 = (unsigned char*)p;
        unsigned* ebuf  = (unsigned*)p; p += (G8_BYTES > EBUF_EXACT ? G8_BYTES : EBUF_EXACT);
        int*      csr   = (int*)p;      p += EBUF_EXACT;
        float*    norm  = (float*)p;    p += (size_t)N_NODES * 4;
        int*   row_beg  = (int*)p;      p += (size_t)N_NODES * 4;
        int*   row_end  = (int*)p;      p += (size_t)N_NODES * 4;
        int*      ghist = (int*)p;      p += NB * 4;
        int*      bbase = (int*)p;      p += (NB + 4) * 4;
        int*      bcur  = (int*)p;      p += NB * 4;
        if (ws_size >= (size_t)(p - (char*)d_ws)) {
            hipMemsetAsync(ghist, 0, NB * sizeof(int), stream);
            a0_hist     <<<(N_EDGES + 4095) / 4096, 256, 0, stream>>>(dst, ghist);
            bscan_kernel<<<1, 1024, 0, stream>>>(ghist, bbase, bcur);
            a1_fill     <<<A1_GRID, A1_BLK, 0, stream>>>(src, dst, bcur, ebuf, 0);
            b1_sort     <<<NB, B1_BLK, 0, stream>>>(ebuf, bbase, nullptr, 0, csr, row_beg, row_end, norm);
            pregemm_mfma<<<PG_NBLK, 256, 0, stream>>>(feat, W, norm, g8);
            gather2     <<<G2_NBLK, 256, 0, stream>>>(g8, norm, feat, row_beg, row_end, csr, out);
            return;
        }
    }

    // ---- last-resort fallback (round-2 path, ~14.8 MB) ----
    {
        char* q = (char*)d_ws;
        int*   deg       = (int*)q;   q += N_NODES * sizeof(int);
        int*   excl      = (int*)q;   q += N_NODES * sizeof(int);
        int*   cursor    = (int*)q;   q += N_NODES * sizeof(int);
        int*   row_start2= (int*)q;   q += (N_NODES + 1) * sizeof(int);
        float* nrm       = (float*)q; q += N_NODES * sizeof(float);
        int*   partials  = (int*)q;   q += 128 * sizeof(int);
        int*   csr2      = (int*)q;

        hipMemsetAsync(deg, 0, (size_t)N_NODES * sizeof(int), stream);
        deg_kernel  <<<N_EDGES / 256, 256, 0, stream>>>(dst, deg);
        scan1_kernel<<<N_SCANB, SCAN_B, 0, stream>>>(deg, excl, partials);
        scan2_kernel<<<1, 128, 0, stream>>>(partials);
        scan3_kernel<<<N_SCANB, SCAN_B, 0, stream>>>(excl, partials, deg,
                                                     row_start2, cursor, nrm);
        fill_kernel <<<N_EDGES / 256, 256, 0, stream>>>(src, dst, cursor, csr2);
        gather_kernel<<<(N_NODES + 3) / 4, 256, 0, stream>>>(feat, nrm, row_start2, csr2, out);
        final_kernel<<<512, 256, 0, stream>>>(feat, W, nrm, out);
    }
}

// Round 14
// 160.067 us; speedup vs baseline: 1.3650x; 1.0196x over previous
//
#include <hip/hip_runtime.h>
#include <hip/hip_fp16.h>
#include <hip/hip_fp8.h>

#define N_NODES 100000
#define N_EDGES 3200000
#define DIM 128
#define NB 1000        // dst buckets
#define NPB 100        // nodes per bucket (NB*NPB == N_NODES exactly)
#define CAP 3840       // fixed slots per bucket: mean 3200, sigma ~57 -> +11.3 sigma
#define SBIN 32        // coarse src bins per node (src>>12 -> 0..24); 1 MB window

typedef _Float16 f16;
typedef f16 f16x8 __attribute__((ext_vector_type(8)));
typedef float f32x4 __attribute__((ext_vector_type(4)));
typedef float f32x2 __attribute__((ext_vector_type(2)));

// dst/100 via magic multiply (exact for dst < 2^30)
__device__ __forceinline__ int bucket_of(int dst) {
    return (int)(((unsigned long long)(unsigned)dst * 42949673ull) >> 32);
}

// ---- fp8 e4m3 (OCP on gfx950) encode/decode, HW cvt with header fallback ----
__device__ __forceinline__ unsigned char f32_to_fp8(float x) {
#if __has_builtin(__builtin_amdgcn_cvt_pk_fp8_f32)
    int r = __builtin_amdgcn_cvt_pk_fp8_f32(x, x, 0, false);
    return (unsigned char)(r & 0xff);
#else
    __hip_fp8_e4m3 q(x);
    return (unsigned char)q.__x;
#endif
}
__device__ __forceinline__ void fp8x4_acc(unsigned u, float& a0, float& a1,
                                          float& a2, float& a3) {
#if __has_builtin(__builtin_amdgcn_cvt_pk_f32_fp8)
    f32x2 lo = __builtin_amdgcn_cvt_pk_f32_fp8((int)u, false);
    f32x2 hi = __builtin_amdgcn_cvt_pk_f32_fp8((int)u, true);
    a0 += lo[0]; a1 += lo[1]; a2 += hi[0]; a3 += hi[1];
#else
    __hip_fp8_e4m3 q0, q1, q2, q3;
    q0.__x = (unsigned char)(u & 0xffu);
    q1.__x = (unsigned char)((u >> 8) & 0xffu);
    q2.__x = (unsigned char)((u >> 16) & 0xffu);
    q3.__x = (unsigned char)((u >> 24) & 0xffu);
    a0 += (float)q0; a1 += (float)q1; a2 += (float)q2; a3 += (float)q3;
#endif
}

// ---- A0 (middle path only): global per-bucket edge counts ----
__global__ void __launch_bounds__(256) a0_hist(const int* __restrict__ dst,
                                               int* __restrict__ ghist) {
    __shared__ int h[NB];
    for (int i = threadIdx.x; i < NB; i += 256) h[i] = 0;
    __syncthreads();
    const int base = blockIdx.x * 4096 + threadIdx.x;
    #pragma unroll
    for (int i = 0; i < 16; ++i) {
        int e = base + i * 256;
        if (e < N_EDGES) atomicAdd(&h[bucket_of(dst[e])], 1);
    }
    __syncthreads();
    for (int i = threadIdx.x; i < NB; i += 256)
        if (h[i]) atomicAdd(&ghist[i], h[i]);
}

// ---- scan of 1000 bucket counts -> base[], cursor[] (middle path only) ----
__global__ void __launch_bounds__(1024) bscan_kernel(const int* __restrict__ ghist,
                                                     int* __restrict__ base,
                                                     int* __restrict__ cursor) {
    __shared__ int buf[1024];
    const int v = (threadIdx.x < NB) ? ghist[threadIdx.x] : 0;
    buf[threadIdx.x] = v;
    __syncthreads();
    for (int off = 1; off < 1024; off <<= 1) {
        int t = (threadIdx.x >= off) ? buf[threadIdx.x - off] : 0;
        __syncthreads();
        buf[threadIdx.x] += t;
        __syncthreads();
    }
    if (threadIdx.x < NB) {
        int excl = buf[threadIdx.x] - v;
        base[threadIdx.x] = excl;
        cursor[threadIdx.x] = excl;
    }
    if (threadIdx.x == NB - 1) base[NB] = buf[threadIdx.x];
}

// ---- A1: LDS-staged bucket grouping; copy-out is thread-per-slot with
// binary search over lexcl -> full lane utilization + ~8-long coalesced runs.
#define A1_CHUNK 8192
#define A1_BLK 1024
#define A1_ITER (A1_CHUNK / A1_BLK)   // 8
__global__ void __launch_bounds__(A1_BLK) a1_fill(const int* __restrict__ src,
                                                  const int* __restrict__ dst,
                                                  int* __restrict__ cursor,
                                                  unsigned* __restrict__ ebuf,
                                                  const int fixed) {
    __shared__ unsigned eloc[A1_CHUNK];       // 32 KB bucket-grouped staging
    __shared__ int h[NB];                     // counts, later reused as rk
    __shared__ int lexcl[NB + 1];             // slot base per bucket + sentinel
    __shared__ int off[NB];                   // global dest base per bucket
    __shared__ int psum[A1_BLK];
    __shared__ int stot;
    const int tid = threadIdx.x;
    for (int i = tid; i < NB; i += A1_BLK) h[i] = 0;
    __syncthreads();
    const int cbase = blockIdx.x * A1_CHUNK;
    int dc[A1_ITER];
    #pragma unroll
    for (int j = 0; j < A1_ITER; ++j) {
        int e = cbase + j * A1_BLK + tid;
        int d = (e < N_EDGES) ? dst[e] : -1;
        dc[j] = d;
        if (d >= 0) atomicAdd(&h[bucket_of(d)], 1);
    }
    __syncthreads();
    // block scan of h -> lexcl
    {
        int v = (tid < NB) ? h[tid] : 0;
        psum[tid] = v;
        __syncthreads();
        for (int o = 1; o < A1_BLK; o <<= 1) {
            int t = (tid >= o) ? psum[tid - o] : 0;
            __syncthreads();
            psum[tid] += t;
            __syncthreads();
        }
        if (tid < NB) lexcl[tid] = psum[tid] - v;
        if (tid == 0) { stot = psum[A1_BLK - 1]; lexcl[NB] = psum[A1_BLK - 1]; }
    }
    __syncthreads();
    // grab global windows (h still live)
    for (int i = tid; i < NB; i += A1_BLK) {
        int c = h[i];
        int o = c ? atomicAdd(&cursor[i], c) : 0;
        off[i] = (fixed ? i * CAP : 0) + o;
    }
    __syncthreads();
    // h dead -> reuse as rank counters
    for (int i = tid; i < NB; i += A1_BLK) h[i] = 0;
    __syncthreads();
    // scatter into LDS (banked, cheap)
    #pragma unroll
    for (int j = 0; j < A1_ITER; ++j) {
        int d = dc[j];
        if (d >= 0) {
            int e = cbase + j * A1_BLK + tid;
            int b = bucket_of(d);
            int r = atomicAdd(&h[b], 1);
            eloc[lexcl[b] + r] = ((unsigned)src[e] << 7) | (unsigned)(d - b * NPB);
        }
    }
    __syncthreads();
    // coalesced copy-out: thread-per-slot; bucket via binary search on lexcl
    const int total = stot;
    for (int i = tid; i < total; i += A1_BLK) {
        unsigned w = eloc[i];
        int lo = 0, hi = NB;                 // find b: lexcl[b] <= i < lexcl[b+1]
        #pragma unroll
        for (int s = 0; s < 10; ++s) {       // 2^10 = 1024 >= NB+1
            int mid = (lo + hi + 1) >> 1;
            if (mid <= NB && lexcl[mid] <= i) lo = mid; else hi = mid - 1;
        }
        int b = lo;
        int gdst = off[b] + (i - lexcl[b]);
        if (!fixed || gdst < (b + 1) * CAP)  // overflow guard (never taken)
            ebuf[gdst] = w;
    }
}

// ---- B1: per-bucket counting sort by (local_dst, src>>12) ------------------
// Place pass scatters into LDS sorted[]; copy-out to csr is fully coalesced.
#define B1_BLK 512
__global__ void __launch_bounds__(B1_BLK) b1_sort(const unsigned* __restrict__ ebuf,
                                                  const int* __restrict__ base,   // exact path
                                                  const int* __restrict__ cnts,   // fixed path
                                                  const int fixed,
                                                  int* __restrict__ csr,
                                                  int* __restrict__ row_beg,
                                                  int* __restrict__ row_end,
                                                  float* __restrict__ norm) {
    __shared__ int hist[NPB * SBIN], cur[NPB * SBIN], psum[B1_BLK];
    __shared__ int sorted[CAP];                    // 15.4 KB staging
    const int b = blockIdx.x, tid = threadIdx.x;
    int beg, cnt;
    if (fixed) { beg = b * CAP; cnt = min(cnts[b], CAP); }
    else       { beg = base[b]; cnt = base[b + 1] - beg; }
    const int end = beg + cnt;
    for (int i = tid; i < NPB * SBIN; i += B1_BLK) { hist[i] = 0; cur[i] = 0; }
    __syncthreads();
    for (int i = beg + tid; i < end; i += B1_BLK) {
        unsigned w = ebuf[i];
        int key = (int)(w & 127u) * SBIN + (int)(w >> 19);   // src>>12
        atomicAdd(&hist[key], 1);
    }
    __syncthreads();
    // in-place exclusive scan of 3200 counters: 7-elem chunks + block scan
    {
        int s = 0;
        const int c0 = tid * 7;
        #pragma unroll
        for (int j = 0; j < 7; ++j) {
            int idx = c0 + j;
            if (idx < NPB * SBIN) { int hh = hist[idx]; hist[idx] = s; s += hh; }
        }
        psum[tid] = s;
    }
    __syncthreads();
    for (int off = 1; off < B1_BLK; off <<= 1) {
        int t = (tid >= off) ? psum[tid - off] : 0;
        __syncthreads();
        psum[tid] += t;
        __syncthreads();
    }
    {
        int add = (tid > 0) ? psum[tid - 1] : 0;
        const int c0 = tid * 7;
        #pragma unroll
        for (int j = 0; j < 7; ++j) {
            int idx = c0 + j;
            if (idx < NPB * SBIN) hist[idx] += add;
        }
    }
    __syncthreads();
    if (tid < NPB) {
        int st = hist[tid * SBIN];
        int nx = (tid == NPB - 1) ? cnt : hist[(tid + 1) * SBIN];
        row_beg[b * NPB + tid] = beg + st;
        row_end[b * NPB + tid] = beg + nx;
        norm[b * NPB + tid] = rsqrtf(fmaxf((float)(nx - st), 1.0f));
    }
    __syncthreads();
    if (cnt <= CAP) {
        for (int i = beg + tid; i < end; i += B1_BLK) {
            unsigned w = ebuf[i];
            int s = (int)(w >> 7);
            int key = (int)(w & 127u) * SBIN + (s >> 12);
            int r = atomicAdd(&cur[key], 1);
            sorted[hist[key] + r] = s;
        }
        __syncthreads();
        for (int i = tid; i < cnt; i += B1_BLK) csr[beg + i] = sorted[i];
    } else {
        for (int i = beg + tid; i < end; i += B1_BLK) {
            unsigned w = ebuf[i];
            int s = (int)(w >> 7);
            int key = (int)(w & 127u) * SBIN + (s >> 12);
            int r = atomicAdd(&cur[key], 1);
            csr[beg + hist[key] + r] = s;
        }
    }
}

// ---- preGEMM via MFMA: g8[n] = fp8(norm[n] * (feat[n] @ W^T)) ---------------
#define PG_NBLK 512
#define PG_NTILE ((N_NODES + 63) / 64)   // 1563, last tile partial
__global__ void __launch_bounds__(256, 2) pregemm_mfma(const float* __restrict__ feat,
                                                       const float* __restrict__ W,
                                                       const float* __restrict__ norm,
                                                       unsigned char* __restrict__ g8) {
    const int wid = threadIdx.x >> 6;
    const int l   = threadIdx.x & 63;
    const int lr  = l & 15;             // A-row / B-col / C-col
    const int lk  = (l >> 4) * 8;       // k-offset base

    f16x8 bf[8][4];
    #pragma unroll
    for (int nt = 0; nt < 8; ++nt) {
        #pragma unroll
        for (int kb = 0; kb < 4; ++kb) {
            const float* wp = W + (size_t)(nt * 16 + lr) * DIM + kb * 32 + lk;
            float4 w0 = *reinterpret_cast<const float4*>(wp);
            float4 w1 = *reinterpret_cast<const float4*>(wp + 4);
            f16x8 t;
            t[0] = (f16)w0.x; t[1] = (f16)w0.y; t[2] = (f16)w0.z; t[3] = (f16)w0.w;
            t[4] = (f16)w1.x; t[5] = (f16)w1.y; t[6] = (f16)w1.z; t[7] = (f16)w1.w;
            bf[nt][kb] = t;
        }
    }

    for (int tile = blockIdx.x; tile < PG_NTILE; tile += PG_NBLK) {
        const int r0 = tile * 64 + wid * 16;
        if (r0 >= N_NODES) continue;
        f32x4 acc[8] = {};
        #pragma unroll
        for (int kb = 0; kb < 4; ++kb) {
            int ar = r0 + lr;
            if (ar >= N_NODES) ar = N_NODES - 1;
            const float* ap = feat + (size_t)ar * DIM + kb * 32 + lk;
            float4 a0 = *reinterpret_cast<const float4*>(ap);
            float4 a1 = *reinterpret_cast<const float4*>(ap + 4);
            f16x8 a;
            a[0] = (f16)a0.x; a[1] = (f16)a0.y; a[2] = (f16)a0.z; a[3] = (f16)a0.w;
            a[4] = (f16)a1.x; a[5] = (f16)a1.y; a[6] = (f16)a1.z; a[7] = (f16)a1.w;
            #pragma unroll
            for (int nt = 0; nt < 8; ++nt)
                acc[nt] = __builtin_amdgcn_mfma_f32_16x16x32_f16(a, bf[nt][kb], acc[nt], 0, 0, 0);
        }
        const int orow0 = r0 + (l >> 4) * 4;
        float nrm[4];
        #pragma unroll
        for (int j = 0; j < 4; ++j)
            nrm[j] = (orow0 + j < N_NODES) ? norm[orow0 + j] : 0.f;
        #pragma unroll
        for (int nt = 0; nt < 8; ++nt) {
            #pragma unroll
            for (int j = 0; j < 4; ++j) {
                int row = orow0 + j;
                if (row < N_NODES)
                    g8[(size_t)row * DIM + nt * 16 + lr] =
                        f32_to_fp8(acc[nt][j] * nrm[j]);
            }
        }
    }
}

// ---- gather2: one wave per node; fp8 rows (128 B); 8 loads in flight --------
#define G2_NBLK (N_NODES / 4)            // 25000, % 8 == 0 (bijective swizzle)
__global__ void __launch_bounds__(256) gather2(const unsigned char* __restrict__ g8,
                                               const float* __restrict__ norm,
                                               const float* __restrict__ feat,
                                               const int* __restrict__ row_beg,
                                               const int* __restrict__ row_end,
                                               const int* __restrict__ csr,
                                               float* __restrict__ out) {
    const int bswz = (blockIdx.x & 7) * (G2_NBLK / 8) + (blockIdx.x >> 3);
    const int n = bswz * 4 + (threadIdx.x >> 6);
    const int l = threadIdx.x & 63;
    const int sub = l >> 5, li = l & 31;
    const int beg = row_beg[n];
    const int end = row_end[n];
    float a0 = 0.f, a1 = 0.f, a2 = 0.f, a3 = 0.f;
    int e = beg;
    for (; e + 15 < end; e += 16) {      // 8 independent in-flight loads
        int s[8];
        #pragma unroll
        for (int j = 0; j < 8; ++j) s[j] = csr[e + 2 * j + sub];
        unsigned u[8];
        #pragma unroll
        for (int j = 0; j < 8; ++j)
            u[j] = reinterpret_cast<const unsigned*>(g8 + (size_t)s[j] * DIM)[li];
        #pragma unroll
        for (int j = 0; j < 8; ++j) fp8x4_acc(u[j], a0, a1, a2, a3);
    }
    for (; e + 7 < end; e += 8) {
        int s[4];
        #pragma unroll
        for (int j = 0; j < 4; ++j) s[j] = csr[e + 2 * j + sub];
        unsigned u[4];
        #pragma unroll
        for (int j = 0; j < 4; ++j)
            u[j] = reinterpret_cast<const unsigned*>(g8 + (size_t)s[j] * DIM)[li];
        #pragma unroll
        for (int j = 0; j < 4; ++j) fp8x4_acc(u[j], a0, a1, a2, a3);
    }
    for (; e + 1 < end; e += 2) {
        const int s = csr[e + sub];
        unsigned u = reinterpret_cast<const unsigned*>(g8 + (size_t)s * DIM)[li];
        fp8x4_acc(u, a0, a1, a2, a3);
    }
    if (e < end) {                       // odd leftover: half 0 only
        const int s = csr[e];
        unsigned u = reinterpret_cast<const unsigned*>(g8 + (size_t)s * DIM)[li];
        if (sub == 0) fp8x4_acc(u, a0, a1, a2, a3);
    }
    // combine the two half-wave partials
    a0 += __shfl_xor(a0, 32);
    a1 += __shfl_xor(a1, 32);
    a2 += __shfl_xor(a2, 32);
    a3 += __shfl_xor(a3, 32);
    if (sub == 0) {
        const float nm = norm[n];
        const float4 f = reinterpret_cast<const float4*>(feat + (size_t)n * DIM)[li];
        float4 o;
        o.x = fmaxf(a0 * nm, 0.f) + f.x;
        o.y = fmaxf(a1 * nm, 0.f) + f.y;
        o.z = fmaxf(a2 * nm, 0.f) + f.z;
        o.w = fmaxf(a3 * nm, 0.f) + f.w;
        reinterpret_cast<float4*>(out + (size_t)n * DIM)[li] = o;
    }
}

// ============================ FALLBACK (round-2 path) =======================
#define SCAN_B 1024
#define N_SCANB ((N_NODES + SCAN_B - 1) / SCAN_B)

__global__ void __launch_bounds__(256) deg_kernel(const int* __restrict__ dst,
                                                  int* __restrict__ deg) {
    int i = blockIdx.x * 256 + threadIdx.x;
    if (i < N_EDGES) atomicAdd(&deg[dst[i]], 1);
}
__global__ void __launch_bounds__(SCAN_B) scan1_kernel(const int* __restrict__ deg,
                                                       int* __restrict__ excl,
                                                       int* __restrict__ partials) {
    __shared__ int buf[SCAN_B];
    const int gid = blockIdx.x * SCAN_B + threadIdx.x;
    const int v = (gid < N_NODES) ? deg[gid] : 0;
    buf[threadIdx.x] = v;
    __syncthreads();
    #pragma unroll
    for (int off = 1; off < SCAN_B; off <<= 1) {
        int t = (threadIdx.x >= off) ? buf[threadIdx.x - off] : 0;
        __syncthreads();
        buf[threadIdx.x] += t;
        __syncthreads();
    }
    if (gid < N_NODES) excl[gid] = buf[threadIdx.x] - v;
    if (threadIdx.x == SCAN_B - 1) partials[blockIdx.x] = buf[threadIdx.x];
}
__global__ void __launch_bounds__(128) scan2_kernel(int* __restrict__ partials) {
    __shared__ int buf[128];
    const int v = (threadIdx.x < N_SCANB) ? partials[threadIdx.x] : 0;
    buf[threadIdx.x] = v;
    __syncthreads();
    #pragma unroll
    for (int off = 1; off < 128; off <<= 1) {
        int t = (threadIdx.x >= off) ? buf[threadIdx.x - off] : 0;
        __syncthreads();
        buf[threadIdx.x] += t;
        __syncthreads();
    }
    if (threadIdx.x < N_SCANB) partials[threadIdx.x] = buf[threadIdx.x] - v;
}
__global__ void __launch_bounds__(SCAN_B) scan3_kernel(
        const int* __restrict__ excl, const int* __restrict__ partials,
        const int* __restrict__ deg,
        int* __restrict__ row_start, int* __restrict__ cursor,
        float* __restrict__ norm) {
    const int gid = blockIdx.x * SCAN_B + threadIdx.x;
    if (gid < N_NODES) {
        const int rs = excl[gid] + partials[blockIdx.x];
        row_start[gid] = rs;
        cursor[gid] = rs;
        norm[gid] = rsqrtf(fmaxf((float)deg[gid], 1.0f));
    }
    if (gid == 0) row_start[N_NODES] = N_EDGES;
}
__global__ void __launch_bounds__(256) fill_kernel(
        const int* __restrict__ src, const int* __restrict__ dst,
        int* __restrict__ cursor, int* __restrict__ csr) {
    int i = blockIdx.x * 256 + threadIdx.x;
    if (i < N_EDGES) {
        int pos = atomicAdd(&cursor[dst[i]], 1);
        csr[pos] = src[i];
    }
}
__global__ void __launch_bounds__(256) gather_kernel(
        const float* __restrict__ feat, const float* __restrict__ norm,
        const int* __restrict__ row_start, const int* __restrict__ csr,
        float* __restrict__ out) {
    const int n = blockIdx.x * 4 + (threadIdx.x >> 6);
    if (n >= N_NODES) return;
    const int lane = threadIdx.x & 63;
    const int beg = row_start[n];
    const int end = row_start[n + 1];
    float2 acc = make_float2(0.f, 0.f);
    int e = beg;
    for (; e + 1 < end; e += 2) {
        const int s0 = csr[e], s1 = csr[e + 1];
        const float w0 = norm[s0], w1 = norm[s1];
        const float2 v0 = reinterpret_cast<const float2*>(feat + (size_t)s0 * DIM)[lane];
        const float2 v1 = reinterpret_cast<const float2*>(feat + (size_t)s1 * DIM)[lane];
        acc.x = fmaf(v0.x, w0, acc.x); acc.y = fmaf(v0.y, w0, acc.y);
        acc.x = fmaf(v1.x, w1, acc.x); acc.y = fmaf(v1.y, w1, acc.y);
    }
    if (e < end) {
        const int s0 = csr[e];
        const float w0 = norm[s0];
        const float2 v0 = reinterpret_cast<const float2*>(feat + (size_t)s0 * DIM)[lane];
        acc.x = fmaf(v0.x, w0, acc.x); acc.y = fmaf(v0.y, w0, acc.y);
    }
    reinterpret_cast<float2*>(out + (size_t)n * DIM)[lane] = acc;
}
__global__ void __launch_bounds__(256) final_kernel(
        const float* __restrict__ feat, const float* __restrict__ W,
        const float* __restrict__ norm, float* __restrict__ out) {
    __shared__ float Wt[DIM * DIM];
    __shared__ float rowbuf[8][DIM];
    for (int idx = threadIdx.x; idx < DIM * DIM; idx += 256)
        Wt[idx] = W[(idx & 127) * DIM + (idx >> 7)];
    const int o  = threadIdx.x & 127;
    const int r0 = (threadIdx.x >> 7) * 4;
    for (int rb = blockIdx.x * 8; rb < N_NODES; rb += gridDim.x * 8) {
        __syncthreads();
        float4 v = reinterpret_cast<const float4*>(out + (size_t)rb * DIM)[threadIdx.x];
        reinterpret_cast<float4*>(&rowbuf[0][0])[threadIdx.x] = v;
        __syncthreads();
        float acc0 = 0.f, acc1 = 0.f, acc2 = 0.f, acc3 = 0.f;
        #pragma unroll 8
        for (int k = 0; k < DIM; ++k) {
            float w = Wt[k * DIM + o];
            acc0 = fmaf(rowbuf[r0 + 0][k], w, acc0);
            acc1 = fmaf(rowbuf[r0 + 1][k], w, acc1);
            acc2 = fmaf(rowbuf[r0 + 2][k], w, acc2);
            acc3 = fmaf(rowbuf[r0 + 3][k], w, acc3);
        }
        float accs[4] = {acc0, acc1, acc2, acc3};
        #pragma unroll
        for (int r = 0; r < 4; ++r) {
            int row = rb + r0 + r;
            float val = fmaxf(accs[r] * norm[row], 0.0f) + feat[(size_t)row * DIM + o];
            out[(size_t)row * DIM + o] = val;
        }
    }
}

// ============================ launch ========================================
extern "C" void kernel_launch(void* const* d_in, const int* in_sizes, int n_in,
                              void* d_out, int out_size, void* d_ws, size_t ws_size,
                              hipStream_t stream) {
    const float* feat = (const float*)d_in[0];
    const float* W    = (const float*)d_in[1];
    const int*   src  = (const int*)d_in[2];
    const int*   dst  = (const int*)d_in[3];
    float* out = (float*)d_out;

    const size_t G8_BYTES   = (size_t)N_NODES * DIM;          // 12.8 MB
    const size_t EBUF_FIX   = (size_t)NB * CAP * 4;           // 15.36 MB
    const size_t EBUF_EXACT = (size_t)N_EDGES * 4;            // 12.8 MB
    const int    A1_GRID    = (N_EDGES + A1_CHUNK - 1) / A1_CHUNK;   // 391

    // ---- fast path (fixed-capacity buckets), ~32 MB ----
    {
        char* p = (char*)d_ws;
        unsigned char* g8 = (unsigned char*)p;
        unsigned* ebuf  = (unsigned*)p; p += (G8_BYTES > EBUF_FIX ? G8_BYTES : EBUF_FIX);
        int*      csr   = (int*)p;      p += EBUF_FIX;
        float*    norm  = (float*)p;    p += (size_t)N_NODES * 4;
        int*   row_beg  = (int*)p;      p += (size_t)N_NODES * 4;
        int*   row_end  = (int*)p;      p += (size_t)N_NODES * 4;
        int*   cursor   = (int*)p;      p += NB * 4;
        if (ws_size >= (size_t)(p - (char*)d_ws)) {
            hipMemsetAsync(cursor, 0, NB * sizeof(int), stream);
            a1_fill     <<<A1_GRID, A1_BLK, 0, stream>>>(src, dst, cursor, ebuf, 1);
            b1_sort     <<<NB, B1_BLK, 0, stream>>>(ebuf, nullptr, cursor, 1, csr, row_beg, row_end, norm);
            pregemm_mfma<<<PG_NBLK, 256, 0, stream>>>(feat, W, norm, g8);   // overwrites ebuf
            gather2     <<<G2_NBLK, 256, 0, stream>>>(g8, norm, feat, row_beg, row_end, csr, out);
            return;
        }
    }

    // ---- middle path (exact bases via a0+bscan), ~28 MB ----
    {
        char* p = (char*)d_ws;
        unsigned char* g8 = (unsigned char*)p;
        unsigned* ebuf  = (unsigned*)p; p += (G8_BYTES > EBUF_EXACT ? G8_BYTES : EBUF_EXACT);
        int*      csr   = (int*)p;      p += EBUF_EXACT;
        float*    norm  = (float*)p;    p += (size_t)N_NODES * 4;
        int*   row_beg  = (int*)p;      p += (size_t)N_NODES * 4;
        int*   row_end  = (int*)p;      p += (size_t)N_NODES * 4;
        int*      ghist = (int*)p;      p += NB * 4;
        int*      bbase = (int*)p;      p += (NB + 4) * 4;
        int*      bcur  = (int*)p;      p += NB * 4;
        if (ws_size >= (size_t)(p - (char*)d_ws)) {
            hipMemsetAsync(ghist, 0, NB * sizeof(int), stream);
            a0_hist     <<<(N_EDGES + 4095) / 4096, 256, 0, stream>>>(dst, ghist);
            bscan_kernel<<<1, 1024, 0, stream>>>(ghist, bbase, bcur);
            a1_fill     <<<A1_GRID, A1_BLK, 0, stream>>>(src, dst, bcur, ebuf, 0);
            b1_sort     <<<NB, B1_BLK, 0, stream>>>(ebuf, bbase, nullptr, 0, csr, row_beg, row_end, norm);
            pregemm_mfma<<<PG_NBLK, 256, 0, stream>>>(feat, W, norm, g8);
            gather2     <<<G2_NBLK, 256, 0, stream>>>(g8, norm, feat, row_beg, row_end, csr, out);
            return;
        }
    }

    // ---- last-resort fallback (round-2 path, ~14.8 MB) ----
    {
        char* q = (char*)d_ws;
        int*   deg       = (int*)q;   q += N_NODES * sizeof(int);
        int*   excl      = (int*)q;   q += N_NODES * sizeof(int);
        int*   cursor    = (int*)q;   q += N_NODES * sizeof(int);
        int*   row_start2= (int*)q;   q += (N_NODES + 1) * sizeof(int);
        float* nrm       = (float*)q; q += N_NODES * sizeof(float);
        int*   partials  = (int*)q;   q += 128 * sizeof(int);
        int*   csr2      = (int*)q;

        hipMemsetAsync(deg, 0, (size_t)N_NODES * sizeof(int), stream);
        deg_kernel  <<<N_EDGES / 256, 256, 0, stream>>>(dst, deg);
        scan1_kernel<<<N_SCANB, SCAN_B, 0, stream>>>(deg, excl, partials);
        scan2_kernel<<<1, 128, 0, stream>>>(partials);
        scan3_kernel<<<N_SCANB, SCAN_B, 0, stream>>>(excl, partials, deg,
                                                     row_start2, cursor, nrm);
        fill_kernel <<<N_EDGES / 256, 256, 0, stream>>>(src, dst, cursor, csr2);
        gather_kernel<<<(N_NODES + 3) / 4, 256, 0, stream>>>(feat, nrm, row_start2, csr2, out);
        final_kernel<<<512, 256, 0, stream>>>(feat, W, nrm, out);
    }
}

// Round 15
// 158.562 us; speedup vs baseline: 1.3779x; 1.0095x over previous
//
#include <hip/hip_runtime.h>
#include <hip/hip_fp16.h>
#include <hip/hip_fp8.h>

#define N_NODES 100000
#define N_EDGES 3200000
#define DIM 128
#define NB 1000        // dst buckets
#define NPB 100        // nodes per bucket (NB*NPB == N_NODES exactly)
#define CAP 3840       // fixed slots per bucket: mean 3200, sigma ~57 -> +11.3 sigma
#define SBIN 32        // coarse src bins per node (src>>12 -> 0..24); 1 MB window

typedef _Float16 f16;
typedef f16 f16x8 __attribute__((ext_vector_type(8)));
typedef float f32x4 __attribute__((ext_vector_type(4)));
typedef float f32x2 __attribute__((ext_vector_type(2)));

// dst/100 via magic multiply (exact for dst < 2^30)
__device__ __forceinline__ int bucket_of(int dst) {
    return (int)(((unsigned long long)(unsigned)dst * 42949673ull) >> 32);
}

// 64-lane inclusive scan, no barriers
__device__ __forceinline__ int wave_incl_scan(int v, int lane) {
    #pragma unroll
    for (int o = 1; o < 64; o <<= 1) {
        int t = __shfl_up(v, o, 64);
        if (lane >= o) v += t;
    }
    return v;
}

// ---- fp8 e4m3 (OCP on gfx950) encode/decode, HW cvt with header fallback ----
__device__ __forceinline__ unsigned char f32_to_fp8(float x) {
#if __has_builtin(__builtin_amdgcn_cvt_pk_fp8_f32)
    int r = __builtin_amdgcn_cvt_pk_fp8_f32(x, x, 0, false);
    return (unsigned char)(r & 0xff);
#else
    __hip_fp8_e4m3 q(x);
    return (unsigned char)q.__x;
#endif
}
__device__ __forceinline__ void fp8x4_acc(unsigned u, float& a0, float& a1,
                                          float& a2, float& a3) {
#if __has_builtin(__builtin_amdgcn_cvt_pk_f32_fp8)
    f32x2 lo = __builtin_amdgcn_cvt_pk_f32_fp8((int)u, false);
    f32x2 hi = __builtin_amdgcn_cvt_pk_f32_fp8((int)u, true);
    a0 += lo[0]; a1 += lo[1]; a2 += hi[0]; a3 += hi[1];
#else
    __hip_fp8_e4m3 q0, q1, q2, q3;
    q0.__x = (unsigned char)(u & 0xffu);
    q1.__x = (unsigned char)((u >> 8) & 0xffu);
    q2.__x = (unsigned char)((u >> 16) & 0xffu);
    q3.__x = (unsigned char)((u >> 24) & 0xffu);
    a0 += (float)q0; a1 += (float)q1; a2 += (float)q2; a3 += (float)q3;
#endif
}

// ---- A0 (middle path only): global per-bucket edge counts ----
__global__ void __launch_bounds__(256) a0_hist(const int* __restrict__ dst,
                                               int* __restrict__ ghist) {
    __shared__ int h[NB];
    for (int i = threadIdx.x; i < NB; i += 256) h[i] = 0;
    __syncthreads();
    const int base = blockIdx.x * 4096 + threadIdx.x;
    #pragma unroll
    for (int i = 0; i < 16; ++i) {
        int e = base + i * 256;
        if (e < N_EDGES) atomicAdd(&h[bucket_of(dst[e])], 1);
    }
    __syncthreads();
    for (int i = threadIdx.x; i < NB; i += 256)
        if (h[i]) atomicAdd(&ghist[i], h[i]);
}

// ---- scan of 1000 bucket counts -> base[], cursor[] (middle path only) ----
__global__ void __launch_bounds__(1024) bscan_kernel(const int* __restrict__ ghist,
                                                     int* __restrict__ base,
                                                     int* __restrict__ cursor) {
    __shared__ int buf[1024];
    const int v = (threadIdx.x < NB) ? ghist[threadIdx.x] : 0;
    buf[threadIdx.x] = v;
    __syncthreads();
    for (int off = 1; off < 1024; off <<= 1) {
        int t = (threadIdx.x >= off) ? buf[threadIdx.x - off] : 0;
        __syncthreads();
        buf[threadIdx.x] += t;
        __syncthreads();
    }
    if (threadIdx.x < NB) {
        int excl = buf[threadIdx.x] - v;
        base[threadIdx.x] = excl;
        cursor[threadIdx.x] = excl;
    }
    if (threadIdx.x == NB - 1) base[NB] = buf[threadIdx.x];
}

// ---- A1: LDS-staged bucket grouping; hierarchical shuffle scan (2 barriers);
// copy-out thread-per-slot with binary search over lexcl.
#define A1_CHUNK 8192
#define A1_BLK 1024
#define A1_ITER (A1_CHUNK / A1_BLK)   // 8
__global__ void __launch_bounds__(A1_BLK) a1_fill(const int* __restrict__ src,
                                                  const int* __restrict__ dst,
                                                  int* __restrict__ cursor,
                                                  unsigned* __restrict__ ebuf,
                                                  const int fixed) {
    __shared__ unsigned eloc[A1_CHUNK];       // 32 KB bucket-grouped staging
    __shared__ int h[NB];                     // counts, later reused as rk
    __shared__ int lexcl[NB + 1];             // slot base per bucket + sentinel
    __shared__ int off[NB];                   // global dest base per bucket
    __shared__ int wtot[16], woff[16];
    __shared__ int stot;
    const int tid = threadIdx.x;
    const int lane = tid & 63, wv = tid >> 6;
    for (int i = tid; i < NB; i += A1_BLK) h[i] = 0;
    __syncthreads();
    const int cbase = blockIdx.x * A1_CHUNK;
    int dc[A1_ITER];
    #pragma unroll
    for (int j = 0; j < A1_ITER; ++j) {
        int e = cbase + j * A1_BLK + tid;
        int d = (e < N_EDGES) ? dst[e] : -1;
        dc[j] = d;
        if (d >= 0) atomicAdd(&h[bucket_of(d)], 1);
    }
    __syncthreads();
    // hierarchical scan of h -> lexcl (exclusive), 2 barriers
    {
        int v = (tid < NB) ? h[tid] : 0;
        int inc = wave_incl_scan(v, lane);
        if (lane == 63) wtot[wv] = inc;
        __syncthreads();
        if (wv == 0) {
            int t = (lane < 16) ? wtot[lane] : 0;
            int winc = wave_incl_scan(t, lane);
            if (lane < 16) woff[lane] = winc - t;   // exclusive wave offsets
            if (lane == 15) stot = winc;            // grand total
        }
        __syncthreads();
        if (tid < NB) lexcl[tid] = inc - v + woff[wv];
        if (tid == 0) lexcl[NB] = stot;
    }
    // grab global windows (h still live; no barrier needed before this —
    // lexcl/off writes are disjoint from h reads)
    for (int i = tid; i < NB; i += A1_BLK) {
        int c = h[i];
        int o = c ? atomicAdd(&cursor[i], c) : 0;
        off[i] = (fixed ? i * CAP : 0) + o;
    }
    __syncthreads();
    // h dead -> reuse as rank counters
    for (int i = tid; i < NB; i += A1_BLK) h[i] = 0;
    __syncthreads();
    // scatter into LDS (banked, cheap)
    #pragma unroll
    for (int j = 0; j < A1_ITER; ++j) {
        int d = dc[j];
        if (d >= 0) {
            int e = cbase + j * A1_BLK + tid;
            int b = bucket_of(d);
            int r = atomicAdd(&h[b], 1);
            eloc[lexcl[b] + r] = ((unsigned)src[e] << 7) | (unsigned)(d - b * NPB);
        }
    }
    __syncthreads();
    // coalesced copy-out: thread-per-slot; bucket via binary search on lexcl
    const int total = stot;
    for (int i = tid; i < total; i += A1_BLK) {
        unsigned w = eloc[i];
        int lo = 0, hi = NB;                 // find b: lexcl[b] <= i < lexcl[b+1]
        #pragma unroll
        for (int s = 0; s < 10; ++s) {       // 2^10 = 1024 >= NB+1
            int mid = (lo + hi + 1) >> 1;
            if (mid <= NB && lexcl[mid] <= i) lo = mid; else hi = mid - 1;
        }
        int b = lo;
        int gdst = off[b] + (i - lexcl[b]);
        if (!fixed || gdst < (b + 1) * CAP)  // overflow guard (never taken)
            ebuf[gdst] = w;
    }
}

// ---- B1: per-bucket counting sort by (local_dst, src>>12) ------------------
// Hierarchical shuffle scan (2 barriers); LDS-staged place + coalesced csr out.
#define B1_BLK 512
__global__ void __launch_bounds__(B1_BLK) b1_sort(const unsigned* __restrict__ ebuf,
                                                  const int* __restrict__ base,   // exact path
                                                  const int* __restrict__ cnts,   // fixed path
                                                  const int fixed,
                                                  int* __restrict__ csr,
                                                  int* __restrict__ row_beg,
                                                  int* __restrict__ row_end,
                                                  float* __restrict__ norm) {
    __shared__ int hist[NPB * SBIN], cur[NPB * SBIN];
    __shared__ int sorted[CAP];                    // 15.4 KB staging
    __shared__ int wtot[8], woff[8];
    const int b = blockIdx.x, tid = threadIdx.x;
    const int lane = tid & 63, wv = tid >> 6;
    int beg, cnt;
    if (fixed) { beg = b * CAP; cnt = min(cnts[b], CAP); }
    else       { beg = base[b]; cnt = base[b + 1] - beg; }
    const int end = beg + cnt;
    for (int i = tid; i < NPB * SBIN; i += B1_BLK) { hist[i] = 0; cur[i] = 0; }
    __syncthreads();
    for (int i = beg + tid; i < end; i += B1_BLK) {
        unsigned w = ebuf[i];
        int key = (int)(w & 127u) * SBIN + (int)(w >> 19);   // src>>12
        atomicAdd(&hist[key], 1);
    }
    __syncthreads();
    // in-place exclusive scan of 3200 counters: 7-elem serial chunks +
    // hierarchical shuffle scan of the 512 chunk totals (2 barriers)
    int s = 0;
    {
        const int c0 = tid * 7;
        #pragma unroll
        for (int j = 0; j < 7; ++j) {
            int idx = c0 + j;
            if (idx < NPB * SBIN) { int hh = hist[idx]; hist[idx] = s; s += hh; }
        }
    }
    int inc = wave_incl_scan(s, lane);
    if (lane == 63) wtot[wv] = inc;
    __syncthreads();
    if (wv == 0) {
        int t = (lane < 8) ? wtot[lane] : 0;
        int winc = wave_incl_scan(t, lane);
        if (lane < 8) woff[lane] = winc - t;
    }
    __syncthreads();
    {
        int add = inc - s + woff[wv];        // exclusive prefix of this chunk
        const int c0 = tid * 7;
        #pragma unroll
        for (int j = 0; j < 7; ++j) {
            int idx = c0 + j;
            if (idx < NPB * SBIN) hist[idx] += add;
        }
    }
    __syncthreads();
    if (tid < NPB) {
        int st = hist[tid * SBIN];
        int nx = (tid == NPB - 1) ? cnt : hist[(tid + 1) * SBIN];
        row_beg[b * NPB + tid] = beg + st;
        row_end[b * NPB + tid] = beg + nx;
        norm[b * NPB + tid] = rsqrtf(fmaxf((float)(nx - st), 1.0f));
    }
    __syncthreads();
    if (cnt <= CAP) {
        for (int i = beg + tid; i < end; i += B1_BLK) {
            unsigned w = ebuf[i];
            int sv = (int)(w >> 7);
            int key = (int)(w & 127u) * SBIN + (sv >> 12);
            int r = atomicAdd(&cur[key], 1);
            sorted[hist[key] + r] = sv;
        }
        __syncthreads();
        for (int i = tid; i < cnt; i += B1_BLK) csr[beg + i] = sorted[i];
    } else {
        for (int i = beg + tid; i < end; i += B1_BLK) {
            unsigned w = ebuf[i];
            int sv = (int)(w >> 7);
            int key = (int)(w & 127u) * SBIN + (sv >> 12);
            int r = atomicAdd(&cur[key], 1);
            csr[beg + hist[key] + r] = sv;
        }
    }
}

// ---- preGEMM via MFMA: g8[n] = fp8(norm[n] * (feat[n] @ W^T)) ---------------
#define PG_NBLK 512
#define PG_NTILE ((N_NODES + 63) / 64)   // 1563, last tile partial
__global__ void __launch_bounds__(256, 2) pregemm_mfma(const float* __restrict__ feat,
                                                       const float* __restrict__ W,
                                                       const float* __restrict__ norm,
                                                       unsigned char* __restrict__ g8) {
    const int wid = threadIdx.x >> 6;
    const int l   = threadIdx.x & 63;
    const int lr  = l & 15;             // A-row / B-col / C-col
    const int lk  = (l >> 4) * 8;       // k-offset base

    f16x8 bf[8][4];
    #pragma unroll
    for (int nt = 0; nt < 8; ++nt) {
        #pragma unroll
        for (int kb = 0; kb < 4; ++kb) {
            const float* wp = W + (size_t)(nt * 16 + lr) * DIM + kb * 32 + lk;
            float4 w0 = *reinterpret_cast<const float4*>(wp);
            float4 w1 = *reinterpret_cast<const float4*>(wp + 4);
            f16x8 t;
            t[0] = (f16)w0.x; t[1] = (f16)w0.y; t[2] = (f16)w0.z; t[3] = (f16)w0.w;
            t[4] = (f16)w1.x; t[5] = (f16)w1.y; t[6] = (f16)w1.z; t[7] = (f16)w1.w;
            bf[nt][kb] = t;
        }
    }

    for (int tile = blockIdx.x; tile < PG_NTILE; tile += PG_NBLK) {
        const int r0 = tile * 64 + wid * 16;
        if (r0 >= N_NODES) continue;
        f32x4 acc[8] = {};
        #pragma unroll
        for (int kb = 0; kb < 4; ++kb) {
            int ar = r0 + lr;
            if (ar >= N_NODES) ar = N_NODES - 1;
            const float* ap = feat + (size_t)ar * DIM + kb * 32 + lk;
            float4 a0 = *reinterpret_cast<const float4*>(ap);
            float4 a1 = *reinterpret_cast<const float4*>(ap + 4);
            f16x8 a;
            a[0] = (f16)a0.x; a[1] = (f16)a0.y; a[2] = (f16)a0.z; a[3] = (f16)a0.w;
            a[4] = (f16)a1.x; a[5] = (f16)a1.y; a[6] = (f16)a1.z; a[7] = (f16)a1.w;
            #pragma unroll
            for (int nt = 0; nt < 8; ++nt)
                acc[nt] = __builtin_amdgcn_mfma_f32_16x16x32_f16(a, bf[nt][kb], acc[nt], 0, 0, 0);
        }
        const int orow0 = r0 + (l >> 4) * 4;
        float nrm[4];
        #pragma unroll
        for (int j = 0; j < 4; ++j)
            nrm[j] = (orow0 + j < N_NODES) ? norm[orow0 + j] : 0.f;
        #pragma unroll
        for (int nt = 0; nt < 8; ++nt) {
            #pragma unroll
            for (int j = 0; j < 4; ++j) {
                int row = orow0 + j;
                if (row < N_NODES)
                    g8[(size_t)row * DIM + nt * 16 + lr] =
                        f32_to_fp8(acc[nt][j] * nrm[j]);
            }
        }
    }
}

// ---- gather2: one wave per node; fp8 rows (128 B); 8 loads in flight --------
#define G2_NBLK (N_NODES / 4)            // 25000, % 8 == 0 (bijective swizzle)
__global__ void __launch_bounds__(256) gather2(const unsigned char* __restrict__ g8,
                                               const float* __restrict__ norm,
                                               const float* __restrict__ feat,
                                               const int* __restrict__ row_beg,
                                               const int* __restrict__ row_end,
                                               const int* __restrict__ csr,
                                               float* __restrict__ out) {
    const int bswz = (blockIdx.x & 7) * (G2_NBLK / 8) + (blockIdx.x >> 3);
    const int n = bswz * 4 + (threadIdx.x >> 6);
    const int l = threadIdx.x & 63;
    const int sub = l >> 5, li = l & 31;
    const int beg = row_beg[n];
    const int end = row_end[n];
    float a0 = 0.f, a1 = 0.f, a2 = 0.f, a3 = 0.f;
    int e = beg;
    for (; e + 15 < end; e += 16) {      // 8 independent in-flight loads
        int s[8];
        #pragma unroll
        for (int j = 0; j < 8; ++j) s[j] = csr[e + 2 * j + sub];
        unsigned u[8];
        #pragma unroll
        for (int j = 0; j < 8; ++j)
            u[j] = reinterpret_cast<const unsigned*>(g8 + (size_t)s[j] * DIM)[li];
        #pragma unroll
        for (int j = 0; j < 8; ++j) fp8x4_acc(u[j], a0, a1, a2, a3);
    }
    for (; e + 7 < end; e += 8) {
        int s[4];
        #pragma unroll
        for (int j = 0; j < 4; ++j) s[j] = csr[e + 2 * j + sub];
        unsigned u[4];
        #pragma unroll
        for (int j = 0; j < 4; ++j)
            u[j] = reinterpret_cast<const unsigned*>(g8 + (size_t)s[j] * DIM)[li];
        #pragma unroll
        for (int j = 0; j < 4; ++j) fp8x4_acc(u[j], a0, a1, a2, a3);
    }
    for (; e + 1 < end; e += 2) {
        const int s = csr[e + sub];
        unsigned u = reinterpret_cast<const unsigned*>(g8 + (size_t)s * DIM)[li];
        fp8x4_acc(u, a0, a1, a2, a3);
    }
    if (e < end) {                       // odd leftover: half 0 only
        const int s = csr[e];
        unsigned u = reinterpret_cast<const unsigned*>(g8 + (size_t)s * DIM)[li];
        if (sub == 0) fp8x4_acc(u, a0, a1, a2, a3);
    }
    // combine the two half-wave partials
    a0 += __shfl_xor(a0, 32);
    a1 += __shfl_xor(a1, 32);
    a2 += __shfl_xor(a2, 32);
    a3 += __shfl_xor(a3, 32);
    if (sub == 0) {
        const float nm = norm[n];
        const float4 f = reinterpret_cast<const float4*>(feat + (size_t)n * DIM)[li];
        float4 o;
        o.x = fmaxf(a0 * nm, 0.f) + f.x;
        o.y = fmaxf(a1 * nm, 0.f) + f.y;
        o.z = fmaxf(a2 * nm, 0.f) + f.z;
        o.w = fmaxf(a3 * nm, 0.f) + f.w;
        reinterpret_cast<float4*>(out + (size_t)n * DIM)[li] = o;
    }
}

// ============================ FALLBACK (round-2 path) =======================
#define SCAN_B 1024
#define N_SCANB ((N_NODES + SCAN_B - 1) / SCAN_B)

__global__ void __launch_bounds__(256) deg_kernel(const int* __restrict__ dst,
                                                  int* __restrict__ deg) {
    int i = blockIdx.x * 256 + threadIdx.x;
    if (i < N_EDGES) atomicAdd(&deg[dst[i]], 1);
}
__global__ void __launch_bounds__(SCAN_B) scan1_kernel(const int* __restrict__ deg,
                                                       int* __restrict__ excl,
                                                       int* __restrict__ partials) {
    __shared__ int buf[SCAN_B];
    const int gid = blockIdx.x * SCAN_B + threadIdx.x;
    const int v = (gid < N_NODES) ? deg[gid] : 0;
    buf[threadIdx.x] = v;
    __syncthreads();
    #pragma unroll
    for (int off = 1; off < SCAN_B; off <<= 1) {
        int t = (threadIdx.x >= off) ? buf[threadIdx.x - off] : 0;
        __syncthreads();
        buf[threadIdx.x] += t;
        __syncthreads();
    }
    if (gid < N_NODES) excl[gid] = buf[threadIdx.x] - v;
    if (threadIdx.x == SCAN_B - 1) partials[blockIdx.x] = buf[threadIdx.x];
}
__global__ void __launch_bounds__(128) scan2_kernel(int* __restrict__ partials) {
    __shared__ int buf[128];
    const int v = (threadIdx.x < N_SCANB) ? partials[threadIdx.x] : 0;
    buf[threadIdx.x] = v;
    __syncthreads();
    #pragma unroll
    for (int off = 1; off < 128; off <<= 1) {
        int t = (threadIdx.x >= off) ? buf[threadIdx.x - off] : 0;
        __syncthreads();
        buf[threadIdx.x] += t;
        __syncthreads();
    }
    if (threadIdx.x < N_SCANB) partials[threadIdx.x] = buf[threadIdx.x] - v;
}
__global__ void __launch_bounds__(SCAN_B) scan3_kernel(
        const int* __restrict__ excl, const int* __restrict__ partials,
        const int* __restrict__ deg,
        int* __restrict__ row_start, int* __restrict__ cursor,
        float* __restrict__ norm) {
    const int gid = blockIdx.x * SCAN_B + threadIdx.x;
    if (gid < N_NODES) {
        const int rs = excl[gid] + partials[blockIdx.x];
        row_start[gid] = rs;
        cursor[gid] = rs;
        norm[gid] = rsqrtf(fmaxf((float)deg[gid], 1.0f));
    }
    if (gid == 0) row_start[N_NODES] = N_EDGES;
}
__global__ void __launch_bounds__(256) fill_kernel(
        const int* __restrict__ src, const int* __restrict__ dst,
        int* __restrict__ cursor, int* __restrict__ csr) {
    int i = blockIdx.x * 256 + threadIdx.x;
    if (i < N_EDGES) {
        int pos = atomicAdd(&cursor[dst[i]], 1);
        csr[pos] = src[i];
    }
}
__global__ void __launch_bounds__(256) gather_kernel(
        const float* __restrict__ feat, const float* __restrict__ norm,
        const int* __restrict__ row_start, const int* __restrict__ csr,
        float* __restrict__ out) {
    const int n = blockIdx.x * 4 + (threadIdx.x >> 6);
    if (n >= N_NODES) return;
    const int lane = threadIdx.x & 63;
    const int beg = row_start[n];
    const int end = row_start[n + 1];
    float2 acc = make_float2(0.f, 0.f);
    int e = beg;
    for (; e + 1 < end; e += 2) {
        const int s0 = csr[e], s1 = csr[e + 1];
        const float w0 = norm[s0], w1 = norm[s1];
        const float2 v0 = reinterpret_cast<const float2*>(feat + (size_t)s0 * DIM)[lane];
        const float2 v1 = reinterpret_cast<const float2*>(feat + (size_t)s1 * DIM)[lane];
        acc.x = fmaf(v0.x, w0, acc.x); acc.y = fmaf(v0.y, w0, acc.y);
        acc.x = fmaf(v1.x, w1, acc.x); acc.y = fmaf(v1.y, w1, acc.y);
    }
    if (e < end) {
        const int s0 = csr[e];
        const float w0 = norm[s0];
        const float2 v0 = reinterpret_cast<const float2*>(feat + (size_t)s0 * DIM)[lane];
        acc.x = fmaf(v0.x, w0, acc.x); acc.y = fmaf(v0.y, w0, acc.y);
    }
    reinterpret_cast<float2*>(out + (size_t)n * DIM)[lane] = acc;
}
__global__ void __launch_bounds__(256) final_kernel(
        const float* __restrict__ feat, const float* __restrict__ W,
        const float* __restrict__ norm, float* __restrict__ out) {
    __shared__ float Wt[DIM * DIM];
    __shared__ float rowbuf[8][DIM];
    for (int idx = threadIdx.x; idx < DIM * DIM; idx += 256)
        Wt[idx] = W[(idx & 127) * DIM + (idx >> 7)];
    const int o  = threadIdx.x & 127;
    const int r0 = (threadIdx.x >> 7) * 4;
    for (int rb = blockIdx.x * 8; rb < N_NODES; rb += gridDim.x * 8) {
        __syncthreads();
        float4 v = reinterpret_cast<const float4*>(out + (size_t)rb * DIM)[threadIdx.x];
        reinterpret_cast<float4*>(&rowbuf[0][0])[threadIdx.x] = v;
        __syncthreads();
        float acc0 = 0.f, acc1 = 0.f, acc2 = 0.f, acc3 = 0.f;
        #pragma unroll 8
        for (int k = 0; k < DIM; ++k) {
            float w = Wt[k * DIM + o];
            acc0 = fmaf(rowbuf[r0 + 0][k], w, acc0);
            acc1 = fmaf(rowbuf[r0 + 1][k], w, acc1);
            acc2 = fmaf(rowbuf[r0 + 2][k], w, acc2);
            acc3 = fmaf(rowbuf[r0 + 3][k], w, acc3);
        }
        float accs[4] = {acc0, acc1, acc2, acc3};
        #pragma unroll
        for (int r = 0; r < 4; ++r) {
            int row = rb + r0 + r;
            float val = fmaxf(accs[r] * norm[row], 0.0f) + feat[(size_t)row * DIM + o];
            out[(size_t)row * DIM + o] = val;
        }
    }
}

// ============================ launch ========================================
extern "C" void kernel_launch(void* const* d_in, const int* in_sizes, int n_in,
                              void* d_out, int out_size, void* d_ws, size_t ws_size,
                              hipStream_t stream) {
    const float* feat = (const float*)d_in[0];
    const float* W    = (const float*)d_in[1];
    const int*   src  = (const int*)d_in[2];
    const int*   dst  = (const int*)d_in[3];
    float* out = (float*)d_out;

    const size_t G8_BYTES   = (size_t)N_NODES * DIM;          // 12.8 MB
    const size_t EBUF_FIX   = (size_t)NB * CAP * 4;           // 15.36 MB
    const size_t EBUF_EXACT = (size_t)N_EDGES * 4;            // 12.8 MB
    const int    A1_GRID    = (N_EDGES + A1_CHUNK - 1) / A1_CHUNK;   // 391

    // ---- fast path (fixed-capacity buckets), ~32 MB ----
    {
        char* p = (char*)d_ws;
        unsigned char* g8 = (unsigned char*)p;
        unsigned* ebuf  = (unsigned*)p; p += (G8_BYTES > EBUF_FIX ? G8_BYTES : EBUF_FIX);
        int*      csr   = (int*)p;      p += EBUF_FIX;
        float*    norm  = (float*)p;    p += (size_t)N_NODES * 4;
        int*   row_beg  = (int*)p;      p += (size_t)N_NODES * 4;
        int*   row_end  = (int*)p;      p += (size_t)N_NODES * 4;
        int*   cursor   = (int*)p;      p += NB * 4;
        if (ws_size >= (size_t)(p - (char*)d_ws)) {
            hipMemsetAsync(cursor, 0, NB * sizeof(int), stream);
            a1_fill     <<<A1_GRID, A1_BLK, 0, stream>>>(src, dst, cursor, ebuf, 1);
            b1_sort     <<<NB, B1_BLK, 0, stream>>>(ebuf, nullptr, cursor, 1, csr, row_beg, row_end, norm);
            pregemm_mfma<<<PG_NBLK, 256, 0, stream>>>(feat, W, norm, g8);   // overwrites ebuf
            gather2     <<<G2_NBLK, 256, 0, stream>>>(g8, norm, feat, row_beg, row_end, csr, out);
            return;
        }
    }

    // ---- middle path (exact bases via a0+bscan), ~28 MB ----
    {
        char* p = (char*)d_ws;
        unsigned char* g8 = (unsigned char*)p;
        unsigned* ebuf  = (unsigned*)p; p += (G8_BYTES > EBUF_EXACT ? G8_BYTES : EBUF_EXACT);
        int*      csr   = (int*)p;      p += EBUF_EXACT;
        float*    norm  = (float*)p;    p += (size_t)N_NODES * 4;
        int*   row_beg  = (int*)p;      p += (size_t)N_NODES * 4;
        int*   row_end  = (int*)p;      p += (size_t)N_NODES * 4;
        int*      ghist = (int*)p;      p += NB * 4;
        int*      bbase = (int*)p;      p += (NB + 4) * 4;
        int*      bcur  = (int*)p;      p += NB * 4;
        if (ws_size >= (size_t)(p - (char*)d_ws)) {
            hipMemsetAsync(ghist, 0, NB * sizeof(int), stream);
            a0_hist     <<<(N_EDGES + 4095) / 4096, 256, 0, stream>>>(dst, ghist);
            bscan_kernel<<<1, 1024, 0, stream>>>(ghist, bbase, bcur);
            a1_fill     <<<A1_GRID, A1_BLK, 0, stream>>>(src, dst, bcur, ebuf, 0);
            b1_sort     <<<NB, B1_BLK, 0, stream>>>(ebuf, bbase, nullptr, 0, csr, row_beg, row_end, norm);
            pregemm_mfma<<<PG_NBLK, 256, 0, stream>>>(feat, W, norm, g8);
            gather2     <<<G2_NBLK, 256, 0, stream>>>(g8, norm, feat, row_beg, row_end, csr, out);
            return;
        }
    }

    // ---- last-resort fallback (round-2 path, ~14.8 MB) ----
    {
        char* q = (char*)d_ws;
        int*   deg       = (int*)q;   q += N_NODES * sizeof(int);
        int*   excl      = (int*)q;   q += N_NODES * sizeof(int);
        int*   cursor    = (int*)q;   q += N_NODES * sizeof(int);
        int*   row_start2= (int*)q;   q += (N_NODES + 1) * sizeof(int);
        float* nrm       = (float*)q; q += N_NODES * sizeof(float);
        int*   partials  = (int*)q;   q += 128 * sizeof(int);
        int*   csr2      = (int*)q;

        hipMemsetAsync(deg, 0, (size_t)N_NODES * sizeof(int), stream);
        deg_kernel  <<<N_EDGES / 256, 256, 0, stream>>>(dst, deg);
        scan1_kernel<<<N_SCANB, SCAN_B, 0, stream>>>(deg, excl, partials);
        scan2_kernel<<<1, 128, 0, stream>>>(partials);
        scan3_kernel<<<N_SCANB, SCAN_B, 0, stream>>>(excl, partials, deg,
                                                     row_start2, cursor, nrm);
        fill_kernel <<<N_EDGES / 256, 256, 0, stream>>>(src, dst, cursor, csr2);
        gather_kernel<<<(N_NODES + 3) / 4, 256, 0, stream>>>(feat, nrm, row_start2, csr2, out);
        final_kernel<<<512, 256, 0, stream>>>(feat, W, nrm, out);
    }
}